// Round 12
// baseline (1969.607 us; speedup 1.0000x reference)
//
#include <hip/hip_runtime.h>
#include <hip/hip_bf16.h>
#include <hip/hip_cooperative_groups.h>

namespace cg = cooperative_groups;

// SRU: T=4096 B=8 D=H=512, two layers.
// R12 = R10 GEMM (63.5us, best) + single cooperative fused scan kernel per layer:
// phase1 summary -> sync -> fixup1 (exclusive prefixes to SEPARATE bf16 Pa/Pb) ->
// sync -> fixup2 -> sync -> apply (x~/f re-read L2-hot; entry = Pb + Pa*Eg).
// Deterministic phases, release fences only (R8 lesson: no spin-polling).

#define T_DIM 4096
#define B_DIM 8
#define H_DIM 512
#define M_DIM (T_DIM * B_DIM)   // 32768 rows
#define N3H 1536                // 3*H
#define K_DIM 512
#define NKT (K_DIM / 64)        // 8 K-tiles
#define NCHUNK 512
#define CLEN (T_DIM / NCHUNK)   // 8
#define NCHAIN (B_DIM * H_DIM)  // 4096
#define NGRP 32
#define GLEN (NCHUNK / NGRP)    // 16
#define SCAN_GRID (NCHUNK * 4)  // 2048 blocks x 128 threads

typedef __attribute__((ext_vector_type(8))) short s16x8;   // 8 bf16 (4 VGPRs)
typedef __attribute__((ext_vector_type(4))) float f32x4;
typedef unsigned short ushort_t;
typedef unsigned int uint_t;

__device__ __forceinline__ float bf2f(ushort_t u) {
    return __uint_as_float(((uint_t)u) << 16);
}
__device__ __forceinline__ ushort_t f2bf(float f) {
    uint_t u = __float_as_uint(f);
    u += 0x7FFFu + ((u >> 16) & 1u);   // RNE
    return (ushort_t)(u >> 16);
}
__device__ __forceinline__ float frcp(float x) { return __builtin_amdgcn_rcpf(x); }
__device__ __forceinline__ float sigm(float z) {
    return frcp(1.0f + __expf(-z));
}
__device__ __forceinline__ float tanh_fast(float z) {
    return 1.0f - 2.0f * frcp(__expf(2.0f * z) + 1.0f);
}

// ---------------- fused fp32 -> bf16 convert for x, W0, W1 ----------------
#define XF4 (M_DIM * K_DIM / 4)          // 4194304 float4
#define WF4 (N3H * K_DIM / 4)            // 196608 float4
__global__ void cvt_all(const float* __restrict__ x, const float* __restrict__ w0,
                        const float* __restrict__ w1, ushort_t* __restrict__ xb,
                        ushort_t* __restrict__ w0b, ushort_t* __restrict__ w1b) {
    int i = blockIdx.x * blockDim.x + threadIdx.x;
    const float* src; ushort_t* dst; int idx;
    if (i < XF4) { src = x; dst = xb; idx = i; }
    else if (i < XF4 + WF4) { src = w0; dst = w0b; idx = i - XF4; }
    else if (i < XF4 + 2 * WF4) { src = w1; dst = w1b; idx = i - XF4 - WF4; }
    else return;
    float4 v = reinterpret_cast<const float4*>(src)[idx];
    ushort4 o;
    o.x = f2bf(v.x); o.y = f2bf(v.y); o.z = f2bf(v.z); o.w = f2bf(v.w);
    reinterpret_cast<ushort4*>(dst)[idx] = o;
}

// ---------------- bf16 GEMM 256x256 tile, BK=64, 8 waves (2Mx4N), 4-phase/K-tile ----------------
// R10 version verbatim (63.5us): A/B dbuf XOR-swizzled in SH during K-loop, then SH
// reused as [256][256] C-tile (col-XOR swizzle) for coalesced dwordx4 stores.
__device__ __forceinline__ s16x8 lds_swz_read(const ushort_t* base, int row, int kb) {
    int byte = (row << 7) + (((kb << 1)) ^ ((row & 7) << 4));
    return *reinterpret_cast<const s16x8*>(reinterpret_cast<const char*>(base) + byte);
}

__global__ __launch_bounds__(512, 2) void gemm_bt256(const ushort_t* __restrict__ A,
                                                     const ushort_t* __restrict__ Bm,
                                                     ushort_t* __restrict__ C) {
    __shared__ ushort_t SH[65536];               // 128 KiB
    const int ntn = N3H >> 8;                    // 6 col tiles
    const int nwg = gridDim.x;                   // 768 (%8==0)
    const int bid = (int)blockIdx.x;
    const int id = (bid & 7) * (nwg >> 3) + (bid >> 3);   // XCD swizzle (bijective)
    const int tm = id / ntn, tn = id % ntn;
    const int row0 = tm << 8, col0 = tn << 8;
    const int tid = threadIdx.x;
    const int wv = tid >> 6, lane = tid & 63;
    const int wm = wv >> 2, wn = wv & 3;         // 2M x 4N waves; wave tile 128x64
    const int l15 = lane & 15;
    const int kgrp = (lane >> 4) << 3;           // 0,8,16,24

    f32x4 acc[8][4] = {};                        // 8 m-frags x 4 n-frags of 16x16

    const int srw = lane >> 3;                   // row within 8-row wave segment
    const int ssl = lane & 7;                    // 16B slot within 128B row

#define A_OFF(buf_, hh_) ((buf_) * 16384 + (hh_) * 8192)
#define B_OFF(buf_, hh_) (32768 + (buf_) * 16384 + (hh_) * 8192)

#define STAGE_H(ISB, GP, BASE0, hh, t_, d_)                                              \
    {                                                                                    \
        _Pragma("unroll")                                                                \
        for (int j = 0; j < 2; ++j) {                                                    \
            const int rl = j * 64 + wv * 8 + srw;                                        \
            const int sl = ssl ^ (rl & 7);                                               \
            const ushort_t* gp_ = (GP) + (size_t)((BASE0) + (hh) * 128 + rl) * K_DIM     \
                                  + (t_) * 64 + (sl << 3);                               \
            ushort_t* dp_ = &SH[((ISB) ? B_OFF(d_, hh) : A_OFF(d_, hh))                  \
                                + (j * 64 + wv * 8) * 64];                               \
            __builtin_amdgcn_global_load_lds(                                            \
                (const __attribute__((address_space(1))) void*)gp_,                      \
                (__attribute__((address_space(3))) void*)dp_, 16, 0, 0);                 \
        }                                                                                \
    }

#define LDA_HALF(mbase_)                                                                 \
    _Pragma("unroll")                                                                    \
    for (int m = 0; m < 4; ++m)                                                          \
        _Pragma("unroll")                                                                \
        for (int kk = 0; kk < 2; ++kk)                                                   \
            af[m][kk] = lds_swz_read(&SH[A_OFF(buf, wm)], (mbase_ + m) * 16 + l15,       \
                                     kk * 32 + kgrp);

#define LDB_PAIR(nbase_)                                                                 \
    _Pragma("unroll")                                                                    \
    for (int n = 0; n < 2; ++n)                                                          \
        _Pragma("unroll")                                                                \
        for (int kk = 0; kk < 2; ++kk)                                                   \
            bfr[(nbase_) + n][kk] = lds_swz_read(&SH[B_OFF(buf, wn >> 1)],               \
                (wn & 1) * 64 + ((nbase_) + n) * 16 + l15, kk * 32 + kgrp);

#define MFMA_Q(mbase_, nbase_)                                                           \
    _Pragma("unroll")                                                                    \
    for (int m = 0; m < 4; ++m)                                                          \
        _Pragma("unroll")                                                                \
        for (int n = 0; n < 2; ++n)                                                      \
            _Pragma("unroll")                                                            \
            for (int kk = 0; kk < 2; ++kk)                                               \
                acc[(mbase_) + m][(nbase_) + n] = __builtin_amdgcn_mfma_f32_16x16x32_bf16( \
                    af[m][kk], bfr[(nbase_) + n][kk], acc[(mbase_) + m][(nbase_) + n],   \
                    0, 0, 0);

    STAGE_H(1, Bm, col0, 0, 0, 0);
    STAGE_H(0, A, row0, 0, 0, 0);
    STAGE_H(1, Bm, col0, 1, 0, 0);
    STAGE_H(0, A, row0, 1, 0, 0);
    STAGE_H(1, Bm, col0, 0, 1, 1);
    STAGE_H(0, A, row0, 0, 1, 1);
    asm volatile("s_waitcnt vmcnt(4)" ::: "memory");
    __builtin_amdgcn_s_barrier();

#pragma unroll
    for (int u = 0; u < NKT; ++u) {
        const int buf = u & 1;
        s16x8 af[4][2], bfr[4][2];

        LDA_HALF(0);
        LDB_PAIR(0);
        if (u + 1 < NKT) { STAGE_H(1, Bm, col0, 1, u + 1, buf ^ 1); }
        __builtin_amdgcn_s_barrier();
        asm volatile("s_waitcnt lgkmcnt(0)" ::: "memory");
        __builtin_amdgcn_s_setprio(1);
        MFMA_Q(0, 0);
        __builtin_amdgcn_s_setprio(0);
        __builtin_amdgcn_s_barrier();

        LDB_PAIR(2);
        if (u + 1 < NKT) { STAGE_H(0, A, row0, 1, u + 1, buf ^ 1); }
        __builtin_amdgcn_s_barrier();
        asm volatile("s_waitcnt lgkmcnt(0)" ::: "memory");
        __builtin_amdgcn_s_setprio(1);
        MFMA_Q(0, 2);
        __builtin_amdgcn_s_setprio(0);
        __builtin_amdgcn_s_barrier();

        LDA_HALF(4);
        if (u + 2 < NKT) { STAGE_H(1, Bm, col0, 0, u + 2, buf); }
        __builtin_amdgcn_s_barrier();
        asm volatile("s_waitcnt lgkmcnt(0)" ::: "memory");
        __builtin_amdgcn_s_setprio(1);
        MFMA_Q(4, 0);
        __builtin_amdgcn_s_setprio(0);
        __builtin_amdgcn_s_barrier();

        if (u + 2 < NKT) { STAGE_H(0, A, row0, 0, u + 2, buf); }
        __builtin_amdgcn_s_barrier();
        __builtin_amdgcn_s_setprio(1);
        MFMA_Q(4, 2);
        __builtin_amdgcn_s_setprio(0);
        if (u + 2 < NKT)      { asm volatile("s_waitcnt vmcnt(4)" ::: "memory"); }
        else if (u + 1 < NKT) { asm volatile("s_waitcnt vmcnt(0)" ::: "memory"); }
        __builtin_amdgcn_s_barrier();
    }
#undef MFMA_Q
#undef LDB_PAIR
#undef LDA_HALF
#undef STAGE_H
#undef A_OFF
#undef B_OFF

    {
        const int crow = (lane >> 4) << 2;
        const int g = (lane >> 4) & 3;
#pragma unroll
        for (int m = 0; m < 8; ++m) {
            const int rowb = wm * 128 + m * 16 + crow;
#pragma unroll
            for (int n = 0; n < 4; ++n) {
                const int pcol = wn * 64 + ((n ^ g) << 4) + l15;
#pragma unroll
                for (int v = 0; v < 4; ++v)
                    SH[(rowb + v) * 256 + pcol] = f2bf(acc[m][n][v]);
            }
        }
        __syncthreads();
#pragma unroll
        for (int i = 0; i < 16; ++i) {
            const int row = i * 16 + (tid >> 5);
            const int colE = (tid & 31) << 3;
            const int pcol = colE ^ (((row >> 2) & 3) << 4);
            s16x8 vv = *reinterpret_cast<const s16x8*>(&SH[row * 256 + pcol]);
            *reinterpret_cast<s16x8*>(&C[(size_t)(row0 + row) * N3H + col0 + colE]) = vv;
        }
    }
}

// ================= cooperative fused scan: summary -> fixup1 -> fixup2 -> apply ==========
// Grid 2048 x 128 (16 waves/CU, co-resident). Single-writer-phase buffers:
// Sa/Sb (p1), Pa/Pb bf16 + Ga/Gb (p2a), Eg (p2b), hout (p3). Release fence before each
// grid.sync; readers never hold stale copies (audit in theory note).
template <bool IN_BF16, bool OUT_BF16>
__global__ __launch_bounds__(128, 4) void scan_coop(
    const ushort_t* __restrict__ U, const float* __restrict__ bias,
    float* __restrict__ Sa, float* __restrict__ Sb,
    ushort_t* __restrict__ Pa, ushort_t* __restrict__ Pb,
    float* __restrict__ Ga, float* __restrict__ Gb, float* __restrict__ Eg,
    const void* __restrict__ xin, void* __restrict__ hout, float* __restrict__ clast) {
    const int bid = (int)blockIdx.x;
    const int tid = threadIdx.x;
    const int chunk = bid >> 2;
    const int bp = bid & 3;
    const int b = bp * 2 + (tid >> 6);
    const int h = (tid & 63) << 3;
    const int cb = chunk * NCHAIN + b * H_DIM + h;
    float fb[8], rb[8];
#pragma unroll
    for (int j = 0; j < 8; ++j) {
        fb[j] = bias[h + j];
        rb[j] = bias[H_DIM + h + j];
    }

    // ---- phase 1: chunk summary (A = prod f, Bv = local state from 0) ----
    {
        float Aa[8] = {1.f, 1.f, 1.f, 1.f, 1.f, 1.f, 1.f, 1.f};
        float Bv[8] = {0.f, 0.f, 0.f, 0.f, 0.f, 0.f, 0.f, 0.f};
        const ushort_t* rp = U + ((size_t)(chunk * CLEN) * B_DIM + b) * N3H + h;
        s16x8 xt = *reinterpret_cast<const s16x8*>(rp);
        s16x8 ft = *reinterpret_cast<const s16x8*>(rp + H_DIM);
#pragma unroll
        for (int s = 0; s < CLEN; ++s) {
            s16x8 xt_n, ft_n;
            if (s + 1 < CLEN) {
                rp += (size_t)B_DIM * N3H;
                xt_n = *reinterpret_cast<const s16x8*>(rp);
                ft_n = *reinterpret_cast<const s16x8*>(rp + H_DIM);
            }
#pragma unroll
            for (int j = 0; j < 8; ++j) {
                float f = sigm(bf2f((ushort_t)ft[j]) + fb[j]);
                Aa[j] *= f;
                Bv[j] = f * Bv[j] + (1.f - f) * bf2f((ushort_t)xt[j]);
            }
            xt = xt_n; ft = ft_n;
        }
        f32x4 oA0 = {Aa[0], Aa[1], Aa[2], Aa[3]}, oA1 = {Aa[4], Aa[5], Aa[6], Aa[7]};
        f32x4 oB0 = {Bv[0], Bv[1], Bv[2], Bv[3]}, oB1 = {Bv[4], Bv[5], Bv[6], Bv[7]};
        *reinterpret_cast<f32x4*>(&Sa[cb]) = oA0;
        *reinterpret_cast<f32x4*>(&Sa[cb + 4]) = oA1;
        *reinterpret_cast<f32x4*>(&Sb[cb]) = oB0;
        *reinterpret_cast<f32x4*>(&Sb[cb + 4]) = oB1;
    }
    __threadfence();
    cg::this_grid().sync();

    // ---- phase 2a: per-group exclusive prefixes -> Pa/Pb (bf16), group summaries -> Ga/Gb
    {
        const int idx = bid * 128 + tid;
        if (idx < NGRP * NCHAIN) {
            const int chain = idx & (NCHAIN - 1);
            const int g = idx >> 12;
            float A = 1.f, B = 0.f;
#pragma unroll
            for (int i = 0; i < GLEN; ++i) {
                const size_t off = (size_t)(g * GLEN + i) * NCHAIN + chain;
                float a = Sa[off], bb = Sb[off];
                Pa[off] = f2bf(A); Pb[off] = f2bf(B);
                B = a * B + bb;
                A = a * A;
            }
            Ga[g * NCHAIN + chain] = A;
            Gb[g * NCHAIN + chain] = B;
        }
    }
    __threadfence();
    cg::this_grid().sync();

    // ---- phase 2b: group-summary scan -> Eg (group entry states), clast ----
    {
        const int idx = bid * 128 + tid;
        if (idx < NCHAIN) {
            float c = 0.f;
#pragma unroll
            for (int g = 0; g < NGRP; ++g) {
                Eg[g * NCHAIN + idx] = c;
                c = Ga[g * NCHAIN + idx] * c + Gb[g * NCHAIN + idx];
            }
            if (clast) clast[idx] = c;
        }
    }
    __threadfence();
    cg::this_grid().sync();

    // ---- phase 3: apply + highway (x~/f rows L2-hot from phase 1) ----
    {
        const int eb = (chunk >> 4) * NCHAIN + b * H_DIM + h;
        float cc[8];
        {
            s16x8 pa0 = *reinterpret_cast<const s16x8*>(&Pa[cb]);
            s16x8 pb0 = *reinterpret_cast<const s16x8*>(&Pb[cb]);
            f32x4 eg0 = *reinterpret_cast<const f32x4*>(&Eg[eb]);
            f32x4 eg1 = *reinterpret_cast<const f32x4*>(&Eg[eb + 4]);
#pragma unroll
            for (int j = 0; j < 4; ++j) {
                cc[j] = bf2f((ushort_t)pb0[j]) + bf2f((ushort_t)pa0[j]) * eg0[j];
                cc[4 + j] = bf2f((ushort_t)pb0[4 + j]) + bf2f((ushort_t)pa0[4 + j]) * eg1[j];
            }
        }
        size_t row = (size_t)(chunk * CLEN) * B_DIM + b;
        const ushort_t* rp = U + row * N3H + h;
        size_t xoff = row * H_DIM + h;

        s16x8 xt = *reinterpret_cast<const s16x8*>(rp);
        s16x8 ft = *reinterpret_cast<const s16x8*>(rp + H_DIM);
        s16x8 rt = *reinterpret_cast<const s16x8*>(rp + 2 * H_DIM);
        float xv[8];
        if (IN_BF16) {
            s16x8 xi = *reinterpret_cast<const s16x8*>((const ushort_t*)xin + xoff);
#pragma unroll
            for (int j = 0; j < 8; ++j) xv[j] = bf2f((ushort_t)xi[j]);
        } else {
            f32x4 a = *reinterpret_cast<const f32x4*>((const float*)xin + xoff);
            f32x4 c2 = *reinterpret_cast<const f32x4*>((const float*)xin + xoff + 4);
#pragma unroll
            for (int j = 0; j < 4; ++j) { xv[j] = a[j]; xv[4 + j] = c2[j]; }
        }

#pragma unroll
        for (int s = 0; s < CLEN; ++s) {
            s16x8 xt_n, ft_n, rt_n;
            float xv_n[8];
            if (s + 1 < CLEN) {
                rp += (size_t)B_DIM * N3H;
                xt_n = *reinterpret_cast<const s16x8*>(rp);
                ft_n = *reinterpret_cast<const s16x8*>(rp + H_DIM);
                rt_n = *reinterpret_cast<const s16x8*>(rp + 2 * H_DIM);
                size_t xo2 = xoff + (size_t)B_DIM * H_DIM;
                if (IN_BF16) {
                    s16x8 xi = *reinterpret_cast<const s16x8*>((const ushort_t*)xin + xo2);
#pragma unroll
                    for (int j = 0; j < 8; ++j) xv_n[j] = bf2f((ushort_t)xi[j]);
                } else {
                    f32x4 a = *reinterpret_cast<const f32x4*>((const float*)xin + xo2);
                    f32x4 c2 = *reinterpret_cast<const f32x4*>((const float*)xin + xo2 + 4);
#pragma unroll
                    for (int j = 0; j < 4; ++j) { xv_n[j] = a[j]; xv_n[4 + j] = c2[j]; }
                }
            }
            float hv[8];
#pragma unroll
            for (int j = 0; j < 8; ++j) {
                float f = sigm(bf2f((ushort_t)ft[j]) + fb[j]);
                cc[j] = f * cc[j] + (1.f - f) * bf2f((ushort_t)xt[j]);
                float r = sigm(bf2f((ushort_t)rt[j]) + rb[j]);
                hv[j] = r * tanh_fast(cc[j]) + (1.f - r) * xv[j];
            }
            if (OUT_BF16) {
                s16x8 o;
#pragma unroll
                for (int j = 0; j < 8; ++j) o[j] = (short)f2bf(hv[j]);
                *reinterpret_cast<s16x8*>((ushort_t*)hout + xoff) = o;
            } else {
                f32x4 o0 = {hv[0], hv[1], hv[2], hv[3]};
                f32x4 o1 = {hv[4], hv[5], hv[6], hv[7]};
                *reinterpret_cast<f32x4*>((float*)hout + xoff) = o0;
                *reinterpret_cast<f32x4*>((float*)hout + xoff + 4) = o1;
            }
            xoff += (size_t)B_DIM * H_DIM;
            xt = xt_n; ft = ft_n; rt = rt_n;
#pragma unroll
            for (int j = 0; j < 8; ++j) xv[j] = xv_n[j];
        }
    }
}

// ================= fallback path (R10 4-kernel chain) =================
__global__ void scan_summary(const ushort_t* __restrict__ U, const float* __restrict__ bias,
                             float* __restrict__ Sa, float* __restrict__ Sb) {
    const int chunk = blockIdx.x >> 2;
    const int bp = blockIdx.x & 3;
    const int tid = threadIdx.x;
    const int b = bp * 2 + (tid >> 6);
    const int h = (tid & 63) << 3;
    float fb[8];
#pragma unroll
    for (int j = 0; j < 8; ++j) fb[j] = bias[h + j];
    float Aa[8] = {1.f, 1.f, 1.f, 1.f, 1.f, 1.f, 1.f, 1.f};
    float Bv[8] = {0.f, 0.f, 0.f, 0.f, 0.f, 0.f, 0.f, 0.f};
    const ushort_t* rp = U + ((size_t)(chunk * CLEN) * B_DIM + b) * N3H + h;
    s16x8 xt = *reinterpret_cast<const s16x8*>(rp);
    s16x8 ft = *reinterpret_cast<const s16x8*>(rp + H_DIM);
#pragma unroll
    for (int s = 0; s < CLEN; ++s) {
        s16x8 xt_n, ft_n;
        if (s + 1 < CLEN) {
            rp += (size_t)B_DIM * N3H;
            xt_n = *reinterpret_cast<const s16x8*>(rp);
            ft_n = *reinterpret_cast<const s16x8*>(rp + H_DIM);
        }
#pragma unroll
        for (int j = 0; j < 8; ++j) {
            float f = sigm(bf2f((ushort_t)ft[j]) + fb[j]);
            Aa[j] *= f;
            Bv[j] = f * Bv[j] + (1.f - f) * bf2f((ushort_t)xt[j]);
        }
        xt = xt_n; ft = ft_n;
    }
    const int cb = chunk * NCHAIN + b * H_DIM + h;
    f32x4 oA0 = {Aa[0], Aa[1], Aa[2], Aa[3]}, oA1 = {Aa[4], Aa[5], Aa[6], Aa[7]};
    f32x4 oB0 = {Bv[0], Bv[1], Bv[2], Bv[3]}, oB1 = {Bv[4], Bv[5], Bv[6], Bv[7]};
    *reinterpret_cast<f32x4*>(&Sa[cb]) = oA0;
    *reinterpret_cast<f32x4*>(&Sa[cb + 4]) = oA1;
    *reinterpret_cast<f32x4*>(&Sb[cb]) = oB0;
    *reinterpret_cast<f32x4*>(&Sb[cb + 4]) = oB1;
}

__global__ void scan_fixup1(float* Sa, float* Sb, ushort_t* __restrict__ Pa,
                            ushort_t* __restrict__ Pb, float* __restrict__ Ga,
                            float* __restrict__ Gb) {
    const int idx = blockIdx.x * blockDim.x + threadIdx.x;
    const int chain = idx & (NCHAIN - 1);
    const int g = idx >> 12;
    float A = 1.f, B = 0.f;
#pragma unroll
    for (int i = 0; i < GLEN; ++i) {
        const size_t off = (size_t)(g * GLEN + i) * NCHAIN + chain;
        float a = Sa[off], b = Sb[off];
        Pa[off] = f2bf(A); Pb[off] = f2bf(B);
        B = a * B + b;
        A = a * A;
    }
    Ga[g * NCHAIN + chain] = A;
    Gb[g * NCHAIN + chain] = B;
}

__global__ void scan_fixup2(const float* __restrict__ Ga, const float* __restrict__ Gb,
                            float* __restrict__ Eg, float* __restrict__ clast) {
    const int chain = blockIdx.x * blockDim.x + threadIdx.x;
    float c = 0.f;
#pragma unroll
    for (int g = 0; g < NGRP; ++g) {
        Eg[g * NCHAIN + chain] = c;
        c = Ga[g * NCHAIN + chain] * c + Gb[g * NCHAIN + chain];
    }
    if (clast) clast[chain] = c;
}

template <bool IN_BF16, bool OUT_BF16>
__global__ void scan_apply(const ushort_t* __restrict__ U, const float* __restrict__ bias,
                           const ushort_t* __restrict__ Pa, const ushort_t* __restrict__ Pb,
                           const float* __restrict__ Eg,
                           const void* __restrict__ xin, void* __restrict__ hout) {
    const int chunk = blockIdx.x >> 2;
    const int bp = blockIdx.x & 3;
    const int tid = threadIdx.x;
    const int b = bp * 2 + (tid >> 6);
    const int h = (tid & 63) << 3;
    const int cb = chunk * NCHAIN + b * H_DIM + h;
    const int eb = (chunk >> 4) * NCHAIN + b * H_DIM + h;
    float cc[8], fb[8], rb[8];
    {
        s16x8 pa0 = *reinterpret_cast<const s16x8*>(&Pa[cb]);
        s16x8 pb0 = *reinterpret_cast<const s16x8*>(&Pb[cb]);
        f32x4 eg0 = *reinterpret_cast<const f32x4*>(&Eg[eb]);
        f32x4 eg1 = *reinterpret_cast<const f32x4*>(&Eg[eb + 4]);
#pragma unroll
        for (int j = 0; j < 4; ++j) {
            cc[j] = bf2f((ushort_t)pb0[j]) + bf2f((ushort_t)pa0[j]) * eg0[j];
            cc[4 + j] = bf2f((ushort_t)pb0[4 + j]) + bf2f((ushort_t)pa0[4 + j]) * eg1[j];
        }
    }
#pragma unroll
    for (int j = 0; j < 8; ++j) {
        fb[j] = bias[h + j];
        rb[j] = bias[H_DIM + h + j];
    }
    size_t row = (size_t)(chunk * CLEN) * B_DIM + b;
    const ushort_t* rp = U + row * N3H + h;
    size_t xoff = row * H_DIM + h;

    s16x8 xt = *reinterpret_cast<const s16x8*>(rp);
    s16x8 ft = *reinterpret_cast<const s16x8*>(rp + H_DIM);
    s16x8 rt = *reinterpret_cast<const s16x8*>(rp + 2 * H_DIM);
    float xv[8];
    if (IN_BF16) {
        s16x8 xi = *reinterpret_cast<const s16x8*>((const ushort_t*)xin + xoff);
#pragma unroll
        for (int j = 0; j < 8; ++j) xv[j] = bf2f((ushort_t)xi[j]);
    } else {
        f32x4 a = *reinterpret_cast<const f32x4*>((const float*)xin + xoff);
        f32x4 c2 = *reinterpret_cast<const f32x4*>((const float*)xin + xoff + 4);
#pragma unroll
        for (int j = 0; j < 4; ++j) { xv[j] = a[j]; xv[4 + j] = c2[j]; }
    }

#pragma unroll
    for (int s = 0; s < CLEN; ++s) {
        s16x8 xt_n, ft_n, rt_n;
        float xv_n[8];
        if (s + 1 < CLEN) {
            rp += (size_t)B_DIM * N3H;
            xt_n = *reinterpret_cast<const s16x8*>(rp);
            ft_n = *reinterpret_cast<const s16x8*>(rp + H_DIM);
            rt_n = *reinterpret_cast<const s16x8*>(rp + 2 * H_DIM);
            size_t xo2 = xoff + (size_t)B_DIM * H_DIM;
            if (IN_BF16) {
                s16x8 xi = *reinterpret_cast<const s16x8*>((const ushort_t*)xin + xo2);
#pragma unroll
                for (int j = 0; j < 8; ++j) xv_n[j] = bf2f((ushort_t)xi[j]);
            } else {
                f32x4 a = *reinterpret_cast<const f32x4*>((const float*)xin + xo2);
                f32x4 c2 = *reinterpret_cast<const f32x4*>((const float*)xin + xo2 + 4);
#pragma unroll
                for (int j = 0; j < 4; ++j) { xv_n[j] = a[j]; xv_n[4 + j] = c2[j]; }
            }
        }
        float hv[8];
#pragma unroll
        for (int j = 0; j < 8; ++j) {
            float f = sigm(bf2f((ushort_t)ft[j]) + fb[j]);
            cc[j] = f * cc[j] + (1.f - f) * bf2f((ushort_t)xt[j]);
            float r = sigm(bf2f((ushort_t)rt[j]) + rb[j]);
            hv[j] = r * tanh_fast(cc[j]) + (1.f - r) * xv[j];
        }
        if (OUT_BF16) {
            s16x8 o;
#pragma unroll
            for (int j = 0; j < 8; ++j) o[j] = (short)f2bf(hv[j]);
            *reinterpret_cast<s16x8*>((ushort_t*)hout + xoff) = o;
        } else {
            f32x4 o0 = {hv[0], hv[1], hv[2], hv[3]};
            f32x4 o1 = {hv[4], hv[5], hv[6], hv[7]};
            *reinterpret_cast<f32x4*>((float*)hout + xoff) = o0;
            *reinterpret_cast<f32x4*>((float*)hout + xoff + 4) = o1;
        }
        xoff += (size_t)B_DIM * H_DIM;
        xt = xt_n; ft = ft_n; rt = rt_n;
#pragma unroll
        for (int j = 0; j < 8; ++j) xv[j] = xv_n[j];
    }
}

extern "C" void kernel_launch(void* const* d_in, const int* in_sizes, int n_in,
                              void* d_out, int out_size, void* d_ws, size_t ws_size,
                              hipStream_t stream) {
    (void)in_sizes; (void)n_in; (void)out_size; (void)ws_size;
    const float* x  = (const float*)d_in[0];   // [T,B,512]
    const float* W0 = (const float*)d_in[1];   // [1536,512]
    const float* b0 = (const float*)d_in[2];   // [1024]
    const float* W1 = (const float*)d_in[3];   // [1536,512]
    const float* b1 = (const float*)d_in[4];   // [1024]
    float* out = (float*)d_out;                // h [T,B,512] fp32, then c_last [B,512] fp32

    // ws layout (bytes); total 163 MiB.
    // [0,32M): xb (bf16 x) -- dead after GEMM1; scan buffers alias here afterwards:
    //   Sa 8M @0, Sb 8M @8M, Pa(bf16) 4M @16M, Pb 4M @20M, Ga .5M @24M, Gb .5M @24.5M,
    //   Eg .5M @25M  (25.5 MiB total, fits).
    char* ws = (char*)d_ws;
    ushort_t* xb  = (ushort_t*)(ws);
    float*    Sa  = (float*)(ws);
    float*    Sb  = (float*)(ws + 8388608);
    ushort_t* Pa  = (ushort_t*)(ws + 16777216);
    ushort_t* Pb  = (ushort_t*)(ws + 20971520);
    float*    Ga  = (float*)(ws + 25165824);
    float*    Gb  = (float*)(ws + 25690112);
    float*    Eg  = (float*)(ws + 26214400);
    ushort_t* h1  = (ushort_t*)(ws + 33554432);   // 32 MiB
    ushort_t* W0b = (ushort_t*)(ws + 67108864);   // 1.5 MiB
    ushort_t* W1b = (ushort_t*)(ws + 68681728);   // 1.5 MiB
    ushort_t* U   = (ushort_t*)(ws + 70254592);   // 96 MiB

    const int cvt_total = XF4 + 2 * WF4;
    cvt_all<<<(cvt_total + 255) / 256, 256, 0, stream>>>(x, W0, W1, xb, W0b, W1b);

    const int gemm_grid = (M_DIM / 256) * (N3H / 256);   // 768 (%8==0)

    // ---- layer 1 ----
    gemm_bt256<<<gemm_grid, 512, 0, stream>>>(xb, W0b, U);
    {
        const ushort_t* Uc = U; const float* bc = b0;
        float* SaC = Sa; float* SbC = Sb; ushort_t* PaC = Pa; ushort_t* PbC = Pb;
        float* GaC = Ga; float* GbC = Gb; float* EgC = Eg;
        const void* xinC = (const void*)x; void* houtC = (void*)h1; float* clC = nullptr;
        void* args[] = {&Uc, &bc, &SaC, &SbC, &PaC, &PbC, &GaC, &GbC, &EgC,
                        &xinC, &houtC, &clC};
        hipError_t e = hipLaunchCooperativeKernel(
            (const void*)scan_coop<false, true>, dim3(SCAN_GRID), dim3(128), args, 0, stream);
        if (e != hipSuccess) {
            scan_summary<<<SCAN_GRID, 128, 0, stream>>>(U, b0, Sa, Sb);
            scan_fixup1<<<NGRP * NCHAIN / 256, 256, 0, stream>>>(Sa, Sb, Pa, Pb, Ga, Gb);
            scan_fixup2<<<NCHAIN / 256, 256, 0, stream>>>(Ga, Gb, Eg, nullptr);
            scan_apply<false, true><<<SCAN_GRID, 128, 0, stream>>>(U, b0, Pa, Pb, Eg,
                                                                   (const void*)x, (void*)h1);
        }
    }

    // ---- layer 2 ----
    gemm_bt256<<<gemm_grid, 512, 0, stream>>>(h1, W1b, U);
    {
        const ushort_t* Uc = U; const float* bc = b1;
        float* SaC = Sa; float* SbC = Sb; ushort_t* PaC = Pa; ushort_t* PbC = Pb;
        float* GaC = Ga; float* GbC = Gb; float* EgC = Eg;
        const void* xinC = (const void*)h1; void* houtC = (void*)out;
        float* clC = out + (size_t)M_DIM * H_DIM;
        void* args[] = {&Uc, &bc, &SaC, &SbC, &PaC, &PbC, &GaC, &GbC, &EgC,
                        &xinC, &houtC, &clC};
        hipError_t e = hipLaunchCooperativeKernel(
            (const void*)scan_coop<true, false>, dim3(SCAN_GRID), dim3(128), args, 0, stream);
        if (e != hipSuccess) {
            scan_summary<<<SCAN_GRID, 128, 0, stream>>>(U, b1, Sa, Sb);
            scan_fixup1<<<NGRP * NCHAIN / 256, 256, 0, stream>>>(Sa, Sb, Pa, Pb, Ga, Gb);
            scan_fixup2<<<NCHAIN / 256, 256, 0, stream>>>(Ga, Gb, Eg,
                                                          out + (size_t)M_DIM * H_DIM);
            scan_apply<true, false><<<SCAN_GRID, 128, 0, stream>>>(U, b1, Pa, Pb, Eg,
                                                                   (const void*)h1, (void*)out);
        }
    }
}

// Round 13
// 279.040 us; speedup vs baseline: 7.0585x; 7.0585x over previous
//
#include <hip/hip_runtime.h>
#include <hip/hip_bf16.h>

// SRU: T=4096 B=8 D=H=512, two layers.
// R13 = R10 (best passing, 270.6us) + two non-temporal cache-policy edits:
//  (1) GEMM C-write NT (stop 98MB C-stream from evicting A/B panels in L2)
//  (2) layer-2 apply's `out` write NT (64MB fp32, never re-read)
// R12 lesson: grid-wide sync (coop or spin) across XCDs is ~100x a dispatch boundary —
// multi-dispatch scan chain is structurally right.

#define T_DIM 4096
#define B_DIM 8
#define H_DIM 512
#define M_DIM (T_DIM * B_DIM)   // 32768 rows
#define N3H 1536                // 3*H
#define K_DIM 512
#define NKT (K_DIM / 64)        // 8 K-tiles
#define NCHUNK 512
#define CLEN (T_DIM / NCHUNK)   // 8
#define NCHAIN (B_DIM * H_DIM)  // 4096
#define NGRP 32
#define GLEN (NCHUNK / NGRP)    // 16

typedef __attribute__((ext_vector_type(8))) short s16x8;   // 8 bf16 (4 VGPRs)
typedef __attribute__((ext_vector_type(4))) float f32x4;
typedef unsigned short ushort_t;
typedef unsigned int uint_t;

__device__ __forceinline__ float bf2f(ushort_t u) {
    return __uint_as_float(((uint_t)u) << 16);
}
__device__ __forceinline__ ushort_t f2bf(float f) {
    uint_t u = __float_as_uint(f);
    u += 0x7FFFu + ((u >> 16) & 1u);   // RNE
    return (ushort_t)(u >> 16);
}
__device__ __forceinline__ float frcp(float x) { return __builtin_amdgcn_rcpf(x); }
__device__ __forceinline__ float sigm(float z) {
    return frcp(1.0f + __expf(-z));
}
__device__ __forceinline__ float tanh_fast(float z) {
    return 1.0f - 2.0f * frcp(__expf(2.0f * z) + 1.0f);
}

// ---------------- fused fp32 -> bf16 convert for x, W0, W1 ----------------
#define XF4 (M_DIM * K_DIM / 4)          // 4194304 float4
#define WF4 (N3H * K_DIM / 4)            // 196608 float4
__global__ void cvt_all(const float* __restrict__ x, const float* __restrict__ w0,
                        const float* __restrict__ w1, ushort_t* __restrict__ xb,
                        ushort_t* __restrict__ w0b, ushort_t* __restrict__ w1b) {
    int i = blockIdx.x * blockDim.x + threadIdx.x;
    const float* src; ushort_t* dst; int idx;
    if (i < XF4) { src = x; dst = xb; idx = i; }
    else if (i < XF4 + WF4) { src = w0; dst = w0b; idx = i - XF4; }
    else if (i < XF4 + 2 * WF4) { src = w1; dst = w1b; idx = i - XF4 - WF4; }
    else return;
    float4 v = reinterpret_cast<const float4*>(src)[idx];
    ushort4 o;
    o.x = f2bf(v.x); o.y = f2bf(v.y); o.z = f2bf(v.z); o.w = f2bf(v.w);
    reinterpret_cast<ushort4*>(dst)[idx] = o;
}

// ---------------- bf16 GEMM 256x256 tile, BK=64, 8 waves (2Mx4N), 4-phase/K-tile ----------------
// R10 structure: A/B dbuf XOR-swizzled in SH during K-loop, then SH reused as
// [256][256] C-tile (col-XOR swizzle) for coalesced dwordx4 stores. R13: C stores NT.
__device__ __forceinline__ s16x8 lds_swz_read(const ushort_t* base, int row, int kb) {
    int byte = (row << 7) + (((kb << 1)) ^ ((row & 7) << 4));
    return *reinterpret_cast<const s16x8*>(reinterpret_cast<const char*>(base) + byte);
}

__global__ __launch_bounds__(512, 2) void gemm_bt256(const ushort_t* __restrict__ A,
                                                     const ushort_t* __restrict__ Bm,
                                                     ushort_t* __restrict__ C) {
    __shared__ ushort_t SH[65536];               // 128 KiB
    const int ntn = N3H >> 8;                    // 6 col tiles
    const int nwg = gridDim.x;                   // 768 (%8==0)
    const int bid = (int)blockIdx.x;
    const int id = (bid & 7) * (nwg >> 3) + (bid >> 3);   // XCD swizzle (bijective)
    const int tm = id / ntn, tn = id % ntn;
    const int row0 = tm << 8, col0 = tn << 8;
    const int tid = threadIdx.x;
    const int wv = tid >> 6, lane = tid & 63;
    const int wm = wv >> 2, wn = wv & 3;         // 2M x 4N waves; wave tile 128x64
    const int l15 = lane & 15;
    const int kgrp = (lane >> 4) << 3;           // 0,8,16,24

    f32x4 acc[8][4] = {};                        // 8 m-frags x 4 n-frags of 16x16

    const int srw = lane >> 3;                   // row within 8-row wave segment
    const int ssl = lane & 7;                    // 16B slot within 128B row

#define A_OFF(buf_, hh_) ((buf_) * 16384 + (hh_) * 8192)
#define B_OFF(buf_, hh_) (32768 + (buf_) * 16384 + (hh_) * 8192)

#define STAGE_H(ISB, GP, BASE0, hh, t_, d_)                                              \
    {                                                                                    \
        _Pragma("unroll")                                                                \
        for (int j = 0; j < 2; ++j) {                                                    \
            const int rl = j * 64 + wv * 8 + srw;                                        \
            const int sl = ssl ^ (rl & 7);                                               \
            const ushort_t* gp_ = (GP) + (size_t)((BASE0) + (hh) * 128 + rl) * K_DIM     \
                                  + (t_) * 64 + (sl << 3);                               \
            ushort_t* dp_ = &SH[((ISB) ? B_OFF(d_, hh) : A_OFF(d_, hh))                  \
                                + (j * 64 + wv * 8) * 64];                               \
            __builtin_amdgcn_global_load_lds(                                            \
                (const __attribute__((address_space(1))) void*)gp_,                      \
                (__attribute__((address_space(3))) void*)dp_, 16, 0, 0);                 \
        }                                                                                \
    }

#define LDA_HALF(mbase_)                                                                 \
    _Pragma("unroll")                                                                    \
    for (int m = 0; m < 4; ++m)                                                          \
        _Pragma("unroll")                                                                \
        for (int kk = 0; kk < 2; ++kk)                                                   \
            af[m][kk] = lds_swz_read(&SH[A_OFF(buf, wm)], (mbase_ + m) * 16 + l15,       \
                                     kk * 32 + kgrp);

#define LDB_PAIR(nbase_)                                                                 \
    _Pragma("unroll")                                                                    \
    for (int n = 0; n < 2; ++n)                                                          \
        _Pragma("unroll")                                                                \
        for (int kk = 0; kk < 2; ++kk)                                                   \
            bfr[(nbase_) + n][kk] = lds_swz_read(&SH[B_OFF(buf, wn >> 1)],               \
                (wn & 1) * 64 + ((nbase_) + n) * 16 + l15, kk * 32 + kgrp);

#define MFMA_Q(mbase_, nbase_)                                                           \
    _Pragma("unroll")                                                                    \
    for (int m = 0; m < 4; ++m)                                                          \
        _Pragma("unroll")                                                                \
        for (int n = 0; n < 2; ++n)                                                      \
            _Pragma("unroll")                                                            \
            for (int kk = 0; kk < 2; ++kk)                                               \
                acc[(mbase_) + m][(nbase_) + n] = __builtin_amdgcn_mfma_f32_16x16x32_bf16( \
                    af[m][kk], bfr[(nbase_) + n][kk], acc[(mbase_) + m][(nbase_) + n],   \
                    0, 0, 0);

    STAGE_H(1, Bm, col0, 0, 0, 0);
    STAGE_H(0, A, row0, 0, 0, 0);
    STAGE_H(1, Bm, col0, 1, 0, 0);
    STAGE_H(0, A, row0, 1, 0, 0);
    STAGE_H(1, Bm, col0, 0, 1, 1);
    STAGE_H(0, A, row0, 0, 1, 1);
    asm volatile("s_waitcnt vmcnt(4)" ::: "memory");
    __builtin_amdgcn_s_barrier();

#pragma unroll
    for (int u = 0; u < NKT; ++u) {
        const int buf = u & 1;
        s16x8 af[4][2], bfr[4][2];

        LDA_HALF(0);
        LDB_PAIR(0);
        if (u + 1 < NKT) { STAGE_H(1, Bm, col0, 1, u + 1, buf ^ 1); }
        __builtin_amdgcn_s_barrier();
        asm volatile("s_waitcnt lgkmcnt(0)" ::: "memory");
        __builtin_amdgcn_s_setprio(1);
        MFMA_Q(0, 0);
        __builtin_amdgcn_s_setprio(0);
        __builtin_amdgcn_s_barrier();

        LDB_PAIR(2);
        if (u + 1 < NKT) { STAGE_H(0, A, row0, 1, u + 1, buf ^ 1); }
        __builtin_amdgcn_s_barrier();
        asm volatile("s_waitcnt lgkmcnt(0)" ::: "memory");
        __builtin_amdgcn_s_setprio(1);
        MFMA_Q(0, 2);
        __builtin_amdgcn_s_setprio(0);
        __builtin_amdgcn_s_barrier();

        LDA_HALF(4);
        if (u + 2 < NKT) { STAGE_H(1, Bm, col0, 0, u + 2, buf); }
        __builtin_amdgcn_s_barrier();
        asm volatile("s_waitcnt lgkmcnt(0)" ::: "memory");
        __builtin_amdgcn_s_setprio(1);
        MFMA_Q(4, 0);
        __builtin_amdgcn_s_setprio(0);
        __builtin_amdgcn_s_barrier();

        if (u + 2 < NKT) { STAGE_H(0, A, row0, 0, u + 2, buf); }
        __builtin_amdgcn_s_barrier();
        __builtin_amdgcn_s_setprio(1);
        MFMA_Q(4, 2);
        __builtin_amdgcn_s_setprio(0);
        if (u + 2 < NKT)      { asm volatile("s_waitcnt vmcnt(4)" ::: "memory"); }
        else if (u + 1 < NKT) { asm volatile("s_waitcnt vmcnt(0)" ::: "memory"); }
        __builtin_amdgcn_s_barrier();
    }
#undef MFMA_Q
#undef LDB_PAIR
#undef LDA_HALF
#undef STAGE_H
#undef A_OFF
#undef B_OFF

    // epilogue: stage C in LDS (col-XOR swizzle, conflict-free), coalesced NT stores
    {
        const int crow = (lane >> 4) << 2;
        const int g = (lane >> 4) & 3;
#pragma unroll
        for (int m = 0; m < 8; ++m) {
            const int rowb = wm * 128 + m * 16 + crow;
#pragma unroll
            for (int n = 0; n < 4; ++n) {
                const int pcol = wn * 64 + ((n ^ g) << 4) + l15;
#pragma unroll
                for (int v = 0; v < 4; ++v)
                    SH[(rowb + v) * 256 + pcol] = f2bf(acc[m][n][v]);
            }
        }
        __syncthreads();
#pragma unroll
        for (int i = 0; i < 16; ++i) {
            const int row = i * 16 + (tid >> 5);
            const int colE = (tid & 31) << 3;
            const int pcol = colE ^ (((row >> 2) & 3) << 4);
            s16x8 vv = *reinterpret_cast<const s16x8*>(&SH[row * 256 + pcol]);
            __builtin_nontemporal_store(
                vv, reinterpret_cast<s16x8*>(&C[(size_t)(row0 + row) * N3H + col0 + colE]));
        }
    }
}

// ---------------- scan pass A: per-chunk summaries, 16B/lane ----------------
__global__ void scan_summary(const ushort_t* __restrict__ U, const float* __restrict__ bias,
                             float* __restrict__ Sa, float* __restrict__ Sb) {
    const int chunk = blockIdx.x >> 2;
    const int bp = blockIdx.x & 3;
    const int tid = threadIdx.x;
    const int b = bp * 2 + (tid >> 6);
    const int h = (tid & 63) << 3;
    float fb[8];
#pragma unroll
    for (int j = 0; j < 8; ++j) fb[j] = bias[h + j];
    float Aa[8] = {1.f, 1.f, 1.f, 1.f, 1.f, 1.f, 1.f, 1.f};
    float Bv[8] = {0.f, 0.f, 0.f, 0.f, 0.f, 0.f, 0.f, 0.f};
    const ushort_t* rp = U + ((size_t)(chunk * CLEN) * B_DIM + b) * N3H + h;
    s16x8 xt = *reinterpret_cast<const s16x8*>(rp);
    s16x8 ft = *reinterpret_cast<const s16x8*>(rp + H_DIM);
#pragma unroll
    for (int s = 0; s < CLEN; ++s) {
        s16x8 xt_n, ft_n;
        if (s + 1 < CLEN) {
            rp += (size_t)B_DIM * N3H;
            xt_n = *reinterpret_cast<const s16x8*>(rp);
            ft_n = *reinterpret_cast<const s16x8*>(rp + H_DIM);
        }
#pragma unroll
        for (int j = 0; j < 8; ++j) {
            float f = sigm(bf2f((ushort_t)ft[j]) + fb[j]);
            Aa[j] *= f;
            Bv[j] = f * Bv[j] + (1.f - f) * bf2f((ushort_t)xt[j]);
        }
        xt = xt_n; ft = ft_n;
    }
    const int cb = chunk * NCHAIN + b * H_DIM + h;
    f32x4 oA0 = {Aa[0], Aa[1], Aa[2], Aa[3]}, oA1 = {Aa[4], Aa[5], Aa[6], Aa[7]};
    f32x4 oB0 = {Bv[0], Bv[1], Bv[2], Bv[3]}, oB1 = {Bv[4], Bv[5], Bv[6], Bv[7]};
    *reinterpret_cast<f32x4*>(&Sa[cb]) = oA0;
    *reinterpret_cast<f32x4*>(&Sa[cb + 4]) = oA1;
    *reinterpret_cast<f32x4*>(&Sb[cb]) = oB0;
    *reinterpret_cast<f32x4*>(&Sb[cb + 4]) = oB1;
}

// ---------------- scan pass B1: per-group local exclusive prefixes (in-place) + group summaries ----------------
__global__ void scan_fixup1(float* Sa, float* Sb, float* __restrict__ Ga, float* __restrict__ Gb) {
    const int idx = blockIdx.x * blockDim.x + threadIdx.x;   // NGRP*4096
    const int chain = idx & (NCHAIN - 1);
    const int g = idx >> 12;
    float A = 1.f, B = 0.f;
#pragma unroll
    for (int i = 0; i < GLEN; ++i) {
        const size_t off = (size_t)(g * GLEN + i) * NCHAIN + chain;
        float a = Sa[off], b = Sb[off];
        Sa[off] = A; Sb[off] = B;       // exclusive prefix (read-before-write, thread-owned)
        B = a * B + b;
        A = a * A;
    }
    Ga[g * NCHAIN + chain] = A;
    Gb[g * NCHAIN + chain] = B;
}

// ---------------- scan pass B2: scan group summaries -> group-entry states ----------------
__global__ void scan_fixup2(const float* __restrict__ Ga, const float* __restrict__ Gb,
                            float* __restrict__ Eg, float* __restrict__ clast) {
    const int chain = blockIdx.x * blockDim.x + threadIdx.x;  // 4096
    float c = 0.f;
#pragma unroll
    for (int g = 0; g < NGRP; ++g) {
        Eg[g * NCHAIN + chain] = c;
        c = Ga[g * NCHAIN + chain] * c + Gb[g * NCHAIN + chain];
    }
    if (clast) clast[chain] = c;   // chain = b*H + h -> [B][H]
}

// ---------------- scan pass C: apply + highway, 16B/lane ----------------
template <bool IN_BF16, bool OUT_BF16>
__global__ void scan_apply(const ushort_t* __restrict__ U,
                           const float* __restrict__ bias,
                           const float* __restrict__ Sa, const float* __restrict__ Sb,
                           const float* __restrict__ Eg,
                           const void* __restrict__ xin, void* __restrict__ hout) {
    const int chunk = blockIdx.x >> 2;
    const int bp = blockIdx.x & 3;
    const int tid = threadIdx.x;
    const int b = bp * 2 + (tid >> 6);
    const int h = (tid & 63) << 3;
    const int cb = chunk * NCHAIN + b * H_DIM + h;
    const int eb = (chunk >> 4) * NCHAIN + b * H_DIM + h;   // group (GLEN=16)
    float cc[8], fb[8], rb[8];
    {
        f32x4 la0 = *reinterpret_cast<const f32x4*>(&Sa[cb]);
        f32x4 la1 = *reinterpret_cast<const f32x4*>(&Sa[cb + 4]);
        f32x4 lb0 = *reinterpret_cast<const f32x4*>(&Sb[cb]);
        f32x4 lb1 = *reinterpret_cast<const f32x4*>(&Sb[cb + 4]);
        f32x4 eg0 = *reinterpret_cast<const f32x4*>(&Eg[eb]);
        f32x4 eg1 = *reinterpret_cast<const f32x4*>(&Eg[eb + 4]);
#pragma unroll
        for (int j = 0; j < 4; ++j) {
            cc[j] = lb0[j] + la0[j] * eg0[j];
            cc[4 + j] = lb1[j] + la1[j] * eg1[j];
        }
    }
#pragma unroll
    for (int j = 0; j < 8; ++j) {
        fb[j] = bias[h + j];
        rb[j] = bias[H_DIM + h + j];
    }
    size_t row = (size_t)(chunk * CLEN) * B_DIM + b;
    const ushort_t* rp = U + row * N3H + h;
    size_t xoff = row * H_DIM + h;

    s16x8 xt = *reinterpret_cast<const s16x8*>(rp);
    s16x8 ft = *reinterpret_cast<const s16x8*>(rp + H_DIM);
    s16x8 rt = *reinterpret_cast<const s16x8*>(rp + 2 * H_DIM);
    float xv[8];
    if (IN_BF16) {
        s16x8 xi = *reinterpret_cast<const s16x8*>((const ushort_t*)xin + xoff);
#pragma unroll
        for (int j = 0; j < 8; ++j) xv[j] = bf2f((ushort_t)xi[j]);
    } else {
        f32x4 a = *reinterpret_cast<const f32x4*>((const float*)xin + xoff);
        f32x4 c2 = *reinterpret_cast<const f32x4*>((const float*)xin + xoff + 4);
#pragma unroll
        for (int j = 0; j < 4; ++j) { xv[j] = a[j]; xv[4 + j] = c2[j]; }
    }

#pragma unroll
    for (int s = 0; s < CLEN; ++s) {
        s16x8 xt_n, ft_n, rt_n;
        float xv_n[8];
        if (s + 1 < CLEN) {
            rp += (size_t)B_DIM * N3H;
            xt_n = *reinterpret_cast<const s16x8*>(rp);
            ft_n = *reinterpret_cast<const s16x8*>(rp + H_DIM);
            rt_n = *reinterpret_cast<const s16x8*>(rp + 2 * H_DIM);
            size_t xo2 = xoff + (size_t)B_DIM * H_DIM;
            if (IN_BF16) {
                s16x8 xi = *reinterpret_cast<const s16x8*>((const ushort_t*)xin + xo2);
#pragma unroll
                for (int j = 0; j < 8; ++j) xv_n[j] = bf2f((ushort_t)xi[j]);
            } else {
                f32x4 a = *reinterpret_cast<const f32x4*>((const float*)xin + xo2);
                f32x4 c2 = *reinterpret_cast<const f32x4*>((const float*)xin + xo2 + 4);
#pragma unroll
                for (int j = 0; j < 4; ++j) { xv_n[j] = a[j]; xv_n[4 + j] = c2[j]; }
            }
        }
        float hv[8];
#pragma unroll
        for (int j = 0; j < 8; ++j) {
            float f = sigm(bf2f((ushort_t)ft[j]) + fb[j]);
            cc[j] = f * cc[j] + (1.f - f) * bf2f((ushort_t)xt[j]);
            float r = sigm(bf2f((ushort_t)rt[j]) + rb[j]);
            hv[j] = r * tanh_fast(cc[j]) + (1.f - r) * xv[j];
        }
        if (OUT_BF16) {
            s16x8 o;
#pragma unroll
            for (int j = 0; j < 8; ++j) o[j] = (short)f2bf(hv[j]);
            *reinterpret_cast<s16x8*>((ushort_t*)hout + xoff) = o;   // h1: re-read by GEMM2
        } else {
            f32x4 o0 = {hv[0], hv[1], hv[2], hv[3]};
            f32x4 o1 = {hv[4], hv[5], hv[6], hv[7]};
            // final output: never re-read -> NT
            __builtin_nontemporal_store(o0, reinterpret_cast<f32x4*>((float*)hout + xoff));
            __builtin_nontemporal_store(o1, reinterpret_cast<f32x4*>((float*)hout + xoff + 4));
        }
        xoff += (size_t)B_DIM * H_DIM;
        xt = xt_n; ft = ft_n; rt = rt_n;
#pragma unroll
        for (int j = 0; j < 8; ++j) xv[j] = xv_n[j];
    }
}

extern "C" void kernel_launch(void* const* d_in, const int* in_sizes, int n_in,
                              void* d_out, int out_size, void* d_ws, size_t ws_size,
                              hipStream_t stream) {
    (void)in_sizes; (void)n_in; (void)out_size; (void)ws_size;
    const float* x  = (const float*)d_in[0];   // [T,B,512]
    const float* W0 = (const float*)d_in[1];   // [1536,512]
    const float* b0 = (const float*)d_in[2];   // [1024]
    const float* W1 = (const float*)d_in[3];   // [1536,512]
    const float* b1 = (const float*)d_in[4];   // [1024]
    float* out = (float*)d_out;                // h [T,B,512] fp32, then c_last [B,512] fp32

    // ws layout (bytes); total 163 MiB.
    // [0,32M): xb (bf16 x) -- dead after GEMM1; Sa/Sb/Ga/Gb/Eg alias here afterwards
    char* ws = (char*)d_ws;
    ushort_t* xb  = (ushort_t*)(ws);
    float*    Sa  = (float*)(ws);                 // 8 MiB
    float*    Sb  = (float*)(ws + 8388608);       // 8 MiB
    float*    Ga  = (float*)(ws + 16777216);      // 512 KiB
    float*    Gb  = (float*)(ws + 17301504);      // 512 KiB
    float*    Eg  = (float*)(ws + 17825792);      // 512 KiB
    ushort_t* h1  = (ushort_t*)(ws + 33554432);   // 32 MiB
    ushort_t* W0b = (ushort_t*)(ws + 67108864);   // 1.5 MiB
    ushort_t* W1b = (ushort_t*)(ws + 68681728);   // 1.5 MiB
    ushort_t* U   = (ushort_t*)(ws + 70254592);   // 96 MiB

    const int cvt_total = XF4 + 2 * WF4;
    cvt_all<<<(cvt_total + 255) / 256, 256, 0, stream>>>(x, W0, W1, xb, W0b, W1b);

    const int gemm_grid = (M_DIM / 256) * (N3H / 256);   // 768 (%8==0)
    const int scan_grid = NCHUNK * 4;                     // 2048 (chunk x batch-pair)

    // ---- layer 1 ----
    gemm_bt256<<<gemm_grid, 512, 0, stream>>>(xb, W0b, U);
    scan_summary<<<scan_grid, 128, 0, stream>>>(U, b0, Sa, Sb);
    scan_fixup1<<<NGRP * NCHAIN / 256, 256, 0, stream>>>(Sa, Sb, Ga, Gb);
    scan_fixup2<<<NCHAIN / 256, 256, 0, stream>>>(Ga, Gb, Eg, nullptr);
    scan_apply<false, true><<<scan_grid, 128, 0, stream>>>(U, b0, Sa, Sb, Eg, (const void*)x, (void*)h1);

    // ---- layer 2 ----
    gemm_bt256<<<gemm_grid, 512, 0, stream>>>(h1, W1b, U);
    scan_summary<<<scan_grid, 128, 0, stream>>>(U, b1, Sa, Sb);
    scan_fixup1<<<NGRP * NCHAIN / 256, 256, 0, stream>>>(Sa, Sb, Ga, Gb);
    scan_fixup2<<<NCHAIN / 256, 256, 0, stream>>>(Ga, Gb, Eg, out + (size_t)M_DIM * H_DIM);
    scan_apply<true, false><<<scan_grid, 128, 0, stream>>>(U, b1, Sa, Sb, Eg, (const void*)h1, (void*)out);
}

// Round 14
// 274.405 us; speedup vs baseline: 7.1777x; 1.0169x over previous
//
#include <hip/hip_runtime.h>
#include <hip/hip_bf16.h>

// SRU: T=4096 B=8 D=H=512, two layers.
// R14 = R10 (best passing, 270.6us) + NT store ONLY on the final fp32 `out` write
// (never re-read). R13 lesson: NT on the GEMM C-write breaks the U->scan_summary
// L2/L3 forwarding path (+8us total) — C stores stay cached.

#define T_DIM 4096
#define B_DIM 8
#define H_DIM 512
#define M_DIM (T_DIM * B_DIM)   // 32768 rows
#define N3H 1536                // 3*H
#define K_DIM 512
#define NKT (K_DIM / 64)        // 8 K-tiles
#define NCHUNK 512
#define CLEN (T_DIM / NCHUNK)   // 8
#define NCHAIN (B_DIM * H_DIM)  // 4096
#define NGRP 32
#define GLEN (NCHUNK / NGRP)    // 16

typedef __attribute__((ext_vector_type(8))) short s16x8;   // 8 bf16 (4 VGPRs)
typedef __attribute__((ext_vector_type(4))) float f32x4;
typedef unsigned short ushort_t;
typedef unsigned int uint_t;

__device__ __forceinline__ float bf2f(ushort_t u) {
    return __uint_as_float(((uint_t)u) << 16);
}
__device__ __forceinline__ ushort_t f2bf(float f) {
    uint_t u = __float_as_uint(f);
    u += 0x7FFFu + ((u >> 16) & 1u);   // RNE
    return (ushort_t)(u >> 16);
}
__device__ __forceinline__ float frcp(float x) { return __builtin_amdgcn_rcpf(x); }
__device__ __forceinline__ float sigm(float z) {
    return frcp(1.0f + __expf(-z));
}
__device__ __forceinline__ float tanh_fast(float z) {
    return 1.0f - 2.0f * frcp(__expf(2.0f * z) + 1.0f);
}

// ---------------- fused fp32 -> bf16 convert for x, W0, W1 ----------------
#define XF4 (M_DIM * K_DIM / 4)          // 4194304 float4
#define WF4 (N3H * K_DIM / 4)            // 196608 float4
__global__ void cvt_all(const float* __restrict__ x, const float* __restrict__ w0,
                        const float* __restrict__ w1, ushort_t* __restrict__ xb,
                        ushort_t* __restrict__ w0b, ushort_t* __restrict__ w1b) {
    int i = blockIdx.x * blockDim.x + threadIdx.x;
    const float* src; ushort_t* dst; int idx;
    if (i < XF4) { src = x; dst = xb; idx = i; }
    else if (i < XF4 + WF4) { src = w0; dst = w0b; idx = i - XF4; }
    else if (i < XF4 + 2 * WF4) { src = w1; dst = w1b; idx = i - XF4 - WF4; }
    else return;
    float4 v = reinterpret_cast<const float4*>(src)[idx];
    ushort4 o;
    o.x = f2bf(v.x); o.y = f2bf(v.y); o.z = f2bf(v.z); o.w = f2bf(v.w);
    reinterpret_cast<ushort4*>(dst)[idx] = o;
}

// ---------------- bf16 GEMM 256x256 tile, BK=64, 8 waves (2Mx4N), 4-phase/K-tile ----------------
// R10 version verbatim (63.5us): A/B dbuf XOR-swizzled in SH during K-loop, then SH
// reused as [256][256] C-tile (col-XOR swizzle) for coalesced dwordx4 stores (cached).
__device__ __forceinline__ s16x8 lds_swz_read(const ushort_t* base, int row, int kb) {
    int byte = (row << 7) + (((kb << 1)) ^ ((row & 7) << 4));
    return *reinterpret_cast<const s16x8*>(reinterpret_cast<const char*>(base) + byte);
}

__global__ __launch_bounds__(512, 2) void gemm_bt256(const ushort_t* __restrict__ A,
                                                     const ushort_t* __restrict__ Bm,
                                                     ushort_t* __restrict__ C) {
    __shared__ ushort_t SH[65536];               // 128 KiB
    const int ntn = N3H >> 8;                    // 6 col tiles
    const int nwg = gridDim.x;                   // 768 (%8==0)
    const int bid = (int)blockIdx.x;
    const int id = (bid & 7) * (nwg >> 3) + (bid >> 3);   // XCD swizzle (bijective)
    const int tm = id / ntn, tn = id % ntn;
    const int row0 = tm << 8, col0 = tn << 8;
    const int tid = threadIdx.x;
    const int wv = tid >> 6, lane = tid & 63;
    const int wm = wv >> 2, wn = wv & 3;         // 2M x 4N waves; wave tile 128x64
    const int l15 = lane & 15;
    const int kgrp = (lane >> 4) << 3;           // 0,8,16,24

    f32x4 acc[8][4] = {};                        // 8 m-frags x 4 n-frags of 16x16

    const int srw = lane >> 3;                   // row within 8-row wave segment
    const int ssl = lane & 7;                    // 16B slot within 128B row

#define A_OFF(buf_, hh_) ((buf_) * 16384 + (hh_) * 8192)
#define B_OFF(buf_, hh_) (32768 + (buf_) * 16384 + (hh_) * 8192)

#define STAGE_H(ISB, GP, BASE0, hh, t_, d_)                                              \
    {                                                                                    \
        _Pragma("unroll")                                                                \
        for (int j = 0; j < 2; ++j) {                                                    \
            const int rl = j * 64 + wv * 8 + srw;                                        \
            const int sl = ssl ^ (rl & 7);                                               \
            const ushort_t* gp_ = (GP) + (size_t)((BASE0) + (hh) * 128 + rl) * K_DIM     \
                                  + (t_) * 64 + (sl << 3);                               \
            ushort_t* dp_ = &SH[((ISB) ? B_OFF(d_, hh) : A_OFF(d_, hh))                  \
                                + (j * 64 + wv * 8) * 64];                               \
            __builtin_amdgcn_global_load_lds(                                            \
                (const __attribute__((address_space(1))) void*)gp_,                      \
                (__attribute__((address_space(3))) void*)dp_, 16, 0, 0);                 \
        }                                                                                \
    }

#define LDA_HALF(mbase_)                                                                 \
    _Pragma("unroll")                                                                    \
    for (int m = 0; m < 4; ++m)                                                          \
        _Pragma("unroll")                                                                \
        for (int kk = 0; kk < 2; ++kk)                                                   \
            af[m][kk] = lds_swz_read(&SH[A_OFF(buf, wm)], (mbase_ + m) * 16 + l15,       \
                                     kk * 32 + kgrp);

#define LDB_PAIR(nbase_)                                                                 \
    _Pragma("unroll")                                                                    \
    for (int n = 0; n < 2; ++n)                                                          \
        _Pragma("unroll")                                                                \
        for (int kk = 0; kk < 2; ++kk)                                                   \
            bfr[(nbase_) + n][kk] = lds_swz_read(&SH[B_OFF(buf, wn >> 1)],               \
                (wn & 1) * 64 + ((nbase_) + n) * 16 + l15, kk * 32 + kgrp);

#define MFMA_Q(mbase_, nbase_)                                                           \
    _Pragma("unroll")                                                                    \
    for (int m = 0; m < 4; ++m)                                                          \
        _Pragma("unroll")                                                                \
        for (int n = 0; n < 2; ++n)                                                      \
            _Pragma("unroll")                                                            \
            for (int kk = 0; kk < 2; ++kk)                                               \
                acc[(mbase_) + m][(nbase_) + n] = __builtin_amdgcn_mfma_f32_16x16x32_bf16( \
                    af[m][kk], bfr[(nbase_) + n][kk], acc[(mbase_) + m][(nbase_) + n],   \
                    0, 0, 0);

    STAGE_H(1, Bm, col0, 0, 0, 0);
    STAGE_H(0, A, row0, 0, 0, 0);
    STAGE_H(1, Bm, col0, 1, 0, 0);
    STAGE_H(0, A, row0, 1, 0, 0);
    STAGE_H(1, Bm, col0, 0, 1, 1);
    STAGE_H(0, A, row0, 0, 1, 1);
    asm volatile("s_waitcnt vmcnt(4)" ::: "memory");
    __builtin_amdgcn_s_barrier();

#pragma unroll
    for (int u = 0; u < NKT; ++u) {
        const int buf = u & 1;
        s16x8 af[4][2], bfr[4][2];

        LDA_HALF(0);
        LDB_PAIR(0);
        if (u + 1 < NKT) { STAGE_H(1, Bm, col0, 1, u + 1, buf ^ 1); }
        __builtin_amdgcn_s_barrier();
        asm volatile("s_waitcnt lgkmcnt(0)" ::: "memory");
        __builtin_amdgcn_s_setprio(1);
        MFMA_Q(0, 0);
        __builtin_amdgcn_s_setprio(0);
        __builtin_amdgcn_s_barrier();

        LDB_PAIR(2);
        if (u + 1 < NKT) { STAGE_H(0, A, row0, 1, u + 1, buf ^ 1); }
        __builtin_amdgcn_s_barrier();
        asm volatile("s_waitcnt lgkmcnt(0)" ::: "memory");
        __builtin_amdgcn_s_setprio(1);
        MFMA_Q(0, 2);
        __builtin_amdgcn_s_setprio(0);
        __builtin_amdgcn_s_barrier();

        LDA_HALF(4);
        if (u + 2 < NKT) { STAGE_H(1, Bm, col0, 0, u + 2, buf); }
        __builtin_amdgcn_s_barrier();
        asm volatile("s_waitcnt lgkmcnt(0)" ::: "memory");
        __builtin_amdgcn_s_setprio(1);
        MFMA_Q(4, 0);
        __builtin_amdgcn_s_setprio(0);
        __builtin_amdgcn_s_barrier();

        if (u + 2 < NKT) { STAGE_H(0, A, row0, 0, u + 2, buf); }
        __builtin_amdgcn_s_barrier();
        __builtin_amdgcn_s_setprio(1);
        MFMA_Q(4, 2);
        __builtin_amdgcn_s_setprio(0);
        if (u + 2 < NKT)      { asm volatile("s_waitcnt vmcnt(4)" ::: "memory"); }
        else if (u + 1 < NKT) { asm volatile("s_waitcnt vmcnt(0)" ::: "memory"); }
        __builtin_amdgcn_s_barrier();
    }
#undef MFMA_Q
#undef LDB_PAIR
#undef LDA_HALF
#undef STAGE_H
#undef A_OFF
#undef B_OFF

    // epilogue: stage C in LDS (col-XOR swizzle, conflict-free), coalesced (cached) stores
    {
        const int crow = (lane >> 4) << 2;
        const int g = (lane >> 4) & 3;
#pragma unroll
        for (int m = 0; m < 8; ++m) {
            const int rowb = wm * 128 + m * 16 + crow;
#pragma unroll
            for (int n = 0; n < 4; ++n) {
                const int pcol = wn * 64 + ((n ^ g) << 4) + l15;
#pragma unroll
                for (int v = 0; v < 4; ++v)
                    SH[(rowb + v) * 256 + pcol] = f2bf(acc[m][n][v]);
            }
        }
        __syncthreads();
#pragma unroll
        for (int i = 0; i < 16; ++i) {
            const int row = i * 16 + (tid >> 5);
            const int colE = (tid & 31) << 3;
            const int pcol = colE ^ (((row >> 2) & 3) << 4);
            s16x8 vv = *reinterpret_cast<const s16x8*>(&SH[row * 256 + pcol]);
            *reinterpret_cast<s16x8*>(&C[(size_t)(row0 + row) * N3H + col0 + colE]) = vv;
        }
    }
}

// ---------------- scan pass A: per-chunk summaries, 16B/lane ----------------
__global__ void scan_summary(const ushort_t* __restrict__ U, const float* __restrict__ bias,
                             float* __restrict__ Sa, float* __restrict__ Sb) {
    const int chunk = blockIdx.x >> 2;
    const int bp = blockIdx.x & 3;
    const int tid = threadIdx.x;
    const int b = bp * 2 + (tid >> 6);
    const int h = (tid & 63) << 3;
    float fb[8];
#pragma unroll
    for (int j = 0; j < 8; ++j) fb[j] = bias[h + j];
    float Aa[8] = {1.f, 1.f, 1.f, 1.f, 1.f, 1.f, 1.f, 1.f};
    float Bv[8] = {0.f, 0.f, 0.f, 0.f, 0.f, 0.f, 0.f, 0.f};
    const ushort_t* rp = U + ((size_t)(chunk * CLEN) * B_DIM + b) * N3H + h;
    s16x8 xt = *reinterpret_cast<const s16x8*>(rp);
    s16x8 ft = *reinterpret_cast<const s16x8*>(rp + H_DIM);
#pragma unroll
    for (int s = 0; s < CLEN; ++s) {
        s16x8 xt_n, ft_n;
        if (s + 1 < CLEN) {
            rp += (size_t)B_DIM * N3H;
            xt_n = *reinterpret_cast<const s16x8*>(rp);
            ft_n = *reinterpret_cast<const s16x8*>(rp + H_DIM);
        }
#pragma unroll
        for (int j = 0; j < 8; ++j) {
            float f = sigm(bf2f((ushort_t)ft[j]) + fb[j]);
            Aa[j] *= f;
            Bv[j] = f * Bv[j] + (1.f - f) * bf2f((ushort_t)xt[j]);
        }
        xt = xt_n; ft = ft_n;
    }
    const int cb = chunk * NCHAIN + b * H_DIM + h;
    f32x4 oA0 = {Aa[0], Aa[1], Aa[2], Aa[3]}, oA1 = {Aa[4], Aa[5], Aa[6], Aa[7]};
    f32x4 oB0 = {Bv[0], Bv[1], Bv[2], Bv[3]}, oB1 = {Bv[4], Bv[5], Bv[6], Bv[7]};
    *reinterpret_cast<f32x4*>(&Sa[cb]) = oA0;
    *reinterpret_cast<f32x4*>(&Sa[cb + 4]) = oA1;
    *reinterpret_cast<f32x4*>(&Sb[cb]) = oB0;
    *reinterpret_cast<f32x4*>(&Sb[cb + 4]) = oB1;
}

// ---------------- scan pass B1: per-group local exclusive prefixes (in-place) + group summaries ----------------
__global__ void scan_fixup1(float* Sa, float* Sb, float* __restrict__ Ga, float* __restrict__ Gb) {
    const int idx = blockIdx.x * blockDim.x + threadIdx.x;   // NGRP*4096
    const int chain = idx & (NCHAIN - 1);
    const int g = idx >> 12;
    float A = 1.f, B = 0.f;
#pragma unroll
    for (int i = 0; i < GLEN; ++i) {
        const size_t off = (size_t)(g * GLEN + i) * NCHAIN + chain;
        float a = Sa[off], b = Sb[off];
        Sa[off] = A; Sb[off] = B;       // exclusive prefix (read-before-write, thread-owned)
        B = a * B + b;
        A = a * A;
    }
    Ga[g * NCHAIN + chain] = A;
    Gb[g * NCHAIN + chain] = B;
}

// ---------------- scan pass B2: scan group summaries -> group-entry states ----------------
__global__ void scan_fixup2(const float* __restrict__ Ga, const float* __restrict__ Gb,
                            float* __restrict__ Eg, float* __restrict__ clast) {
    const int chain = blockIdx.x * blockDim.x + threadIdx.x;  // 4096
    float c = 0.f;
#pragma unroll
    for (int g = 0; g < NGRP; ++g) {
        Eg[g * NCHAIN + chain] = c;
        c = Ga[g * NCHAIN + chain] * c + Gb[g * NCHAIN + chain];
    }
    if (clast) clast[chain] = c;   // chain = b*H + h -> [B][H]
}

// ---------------- scan pass C: apply + highway, 16B/lane ----------------
template <bool IN_BF16, bool OUT_BF16>
__global__ void scan_apply(const ushort_t* __restrict__ U,
                           const float* __restrict__ bias,
                           const float* __restrict__ Sa, const float* __restrict__ Sb,
                           const float* __restrict__ Eg,
                           const void* __restrict__ xin, void* __restrict__ hout) {
    const int chunk = blockIdx.x >> 2;
    const int bp = blockIdx.x & 3;
    const int tid = threadIdx.x;
    const int b = bp * 2 + (tid >> 6);
    const int h = (tid & 63) << 3;
    const int cb = chunk * NCHAIN + b * H_DIM + h;
    const int eb = (chunk >> 4) * NCHAIN + b * H_DIM + h;   // group (GLEN=16)
    float cc[8], fb[8], rb[8];
    {
        f32x4 la0 = *reinterpret_cast<const f32x4*>(&Sa[cb]);
        f32x4 la1 = *reinterpret_cast<const f32x4*>(&Sa[cb + 4]);
        f32x4 lb0 = *reinterpret_cast<const f32x4*>(&Sb[cb]);
        f32x4 lb1 = *reinterpret_cast<const f32x4*>(&Sb[cb + 4]);
        f32x4 eg0 = *reinterpret_cast<const f32x4*>(&Eg[eb]);
        f32x4 eg1 = *reinterpret_cast<const f32x4*>(&Eg[eb + 4]);
#pragma unroll
        for (int j = 0; j < 4; ++j) {
            cc[j] = lb0[j] + la0[j] * eg0[j];
            cc[4 + j] = lb1[j] + la1[j] * eg1[j];
        }
    }
#pragma unroll
    for (int j = 0; j < 8; ++j) {
        fb[j] = bias[h + j];
        rb[j] = bias[H_DIM + h + j];
    }
    size_t row = (size_t)(chunk * CLEN) * B_DIM + b;
    const ushort_t* rp = U + row * N3H + h;
    size_t xoff = row * H_DIM + h;

    s16x8 xt = *reinterpret_cast<const s16x8*>(rp);
    s16x8 ft = *reinterpret_cast<const s16x8*>(rp + H_DIM);
    s16x8 rt = *reinterpret_cast<const s16x8*>(rp + 2 * H_DIM);
    float xv[8];
    if (IN_BF16) {
        s16x8 xi = *reinterpret_cast<const s16x8*>((const ushort_t*)xin + xoff);
#pragma unroll
        for (int j = 0; j < 8; ++j) xv[j] = bf2f((ushort_t)xi[j]);
    } else {
        f32x4 a = *reinterpret_cast<const f32x4*>((const float*)xin + xoff);
        f32x4 c2 = *reinterpret_cast<const f32x4*>((const float*)xin + xoff + 4);
#pragma unroll
        for (int j = 0; j < 4; ++j) { xv[j] = a[j]; xv[4 + j] = c2[j]; }
    }

#pragma unroll
    for (int s = 0; s < CLEN; ++s) {
        s16x8 xt_n, ft_n, rt_n;
        float xv_n[8];
        if (s + 1 < CLEN) {
            rp += (size_t)B_DIM * N3H;
            xt_n = *reinterpret_cast<const s16x8*>(rp);
            ft_n = *reinterpret_cast<const s16x8*>(rp + H_DIM);
            rt_n = *reinterpret_cast<const s16x8*>(rp + 2 * H_DIM);
            size_t xo2 = xoff + (size_t)B_DIM * H_DIM;
            if (IN_BF16) {
                s16x8 xi = *reinterpret_cast<const s16x8*>((const ushort_t*)xin + xo2);
#pragma unroll
                for (int j = 0; j < 8; ++j) xv_n[j] = bf2f((ushort_t)xi[j]);
            } else {
                f32x4 a = *reinterpret_cast<const f32x4*>((const float*)xin + xo2);
                f32x4 c2 = *reinterpret_cast<const f32x4*>((const float*)xin + xo2 + 4);
#pragma unroll
                for (int j = 0; j < 4; ++j) { xv_n[j] = a[j]; xv_n[4 + j] = c2[j]; }
            }
        }
        float hv[8];
#pragma unroll
        for (int j = 0; j < 8; ++j) {
            float f = sigm(bf2f((ushort_t)ft[j]) + fb[j]);
            cc[j] = f * cc[j] + (1.f - f) * bf2f((ushort_t)xt[j]);
            float r = sigm(bf2f((ushort_t)rt[j]) + rb[j]);
            hv[j] = r * tanh_fast(cc[j]) + (1.f - r) * xv[j];
        }
        if (OUT_BF16) {
            s16x8 o;
#pragma unroll
            for (int j = 0; j < 8; ++j) o[j] = (short)f2bf(hv[j]);
            *reinterpret_cast<s16x8*>((ushort_t*)hout + xoff) = o;   // h1: re-read by GEMM2
        } else {
            f32x4 o0 = {hv[0], hv[1], hv[2], hv[3]};
            f32x4 o1 = {hv[4], hv[5], hv[6], hv[7]};
            // final output: never re-read -> NT keeps U/r-part resident in L2
            __builtin_nontemporal_store(o0, reinterpret_cast<f32x4*>((float*)hout + xoff));
            __builtin_nontemporal_store(o1, reinterpret_cast<f32x4*>((float*)hout + xoff + 4));
        }
        xoff += (size_t)B_DIM * H_DIM;
        xt = xt_n; ft = ft_n; rt = rt_n;
#pragma unroll
        for (int j = 0; j < 8; ++j) xv[j] = xv_n[j];
    }
}

extern "C" void kernel_launch(void* const* d_in, const int* in_sizes, int n_in,
                              void* d_out, int out_size, void* d_ws, size_t ws_size,
                              hipStream_t stream) {
    (void)in_sizes; (void)n_in; (void)out_size; (void)ws_size;
    const float* x  = (const float*)d_in[0];   // [T,B,512]
    const float* W0 = (const float*)d_in[1];   // [1536,512]
    const float* b0 = (const float*)d_in[2];   // [1024]
    const float* W1 = (const float*)d_in[3];   // [1536,512]
    const float* b1 = (const float*)d_in[4];   // [1024]
    float* out = (float*)d_out;                // h [T,B,512] fp32, then c_last [B,512] fp32

    // ws layout (bytes); total 163 MiB.
    // [0,32M): xb (bf16 x) -- dead after GEMM1; Sa/Sb/Ga/Gb/Eg alias here afterwards
    char* ws = (char*)d_ws;
    ushort_t* xb  = (ushort_t*)(ws);
    float*    Sa  = (float*)(ws);                 // 8 MiB
    float*    Sb  = (float*)(ws + 8388608);       // 8 MiB
    float*    Ga  = (float*)(ws + 16777216);      // 512 KiB
    float*    Gb  = (float*)(ws + 17301504);      // 512 KiB
    float*    Eg  = (float*)(ws + 17825792);      // 512 KiB
    ushort_t* h1  = (ushort_t*)(ws + 33554432);   // 32 MiB
    ushort_t* W0b = (ushort_t*)(ws + 67108864);   // 1.5 MiB
    ushort_t* W1b = (ushort_t*)(ws + 68681728);   // 1.5 MiB
    ushort_t* U   = (ushort_t*)(ws + 70254592);   // 96 MiB

    const int cvt_total = XF4 + 2 * WF4;
    cvt_all<<<(cvt_total + 255) / 256, 256, 0, stream>>>(x, W0, W1, xb, W0b, W1b);

    const int gemm_grid = (M_DIM / 256) * (N3H / 256);   // 768 (%8==0)
    const int scan_grid = NCHUNK * 4;                     // 2048 (chunk x batch-pair)

    // ---- layer 1 ----
    gemm_bt256<<<gemm_grid, 512, 0, stream>>>(xb, W0b, U);
    scan_summary<<<scan_grid, 128, 0, stream>>>(U, b0, Sa, Sb);
    scan_fixup1<<<NGRP * NCHAIN / 256, 256, 0, stream>>>(Sa, Sb, Ga, Gb);
    scan_fixup2<<<NCHAIN / 256, 256, 0, stream>>>(Ga, Gb, Eg, nullptr);
    scan_apply<false, true><<<scan_grid, 128, 0, stream>>>(U, b0, Sa, Sb, Eg, (const void*)x, (void*)h1);

    // ---- layer 2 ----
    gemm_bt256<<<gemm_grid, 512, 0, stream>>>(h1, W1b, U);
    scan_summary<<<scan_grid, 128, 0, stream>>>(U, b1, Sa, Sb);
    scan_fixup1<<<NGRP * NCHAIN / 256, 256, 0, stream>>>(Sa, Sb, Ga, Gb);
    scan_fixup2<<<NCHAIN / 256, 256, 0, stream>>>(Ga, Gb, Eg, out + (size_t)M_DIM * H_DIM);
    scan_apply<true, false><<<scan_grid, 128, 0, stream>>>(U, b1, Sa, Sb, Eg, (const void*)h1, (void*)out);
}

// Round 15
// 269.437 us; speedup vs baseline: 7.3101x; 1.0184x over previous
//
#include <hip/hip_runtime.h>
#include <hip/hip_bf16.h>

// SRU: T=4096 B=8 D=H=512, two layers. FINAL = R10 exactly (best measured, 270.6us).
// Per layer: bf16 MFMA GEMM 256^2 4-phase w/ LDS-staged coalesced C epilogue (63.5us)
// -> 4-dispatch chunked parallel linear scan (16B/lane, rcp-based transcendentals).
// Levers tried and rejected with measured mechanisms: gate-fusion in GEMM epilogue
// (+5us: epilogue VALU un-overlapped), coop grid-sync scan (7x: cross-XCD sync),
// look-back scan (2.5x: acquire-spin invalidates L2), NT on C (+8us: breaks U->scan
// L2/L3 forwarding), NT on out (+4us: loses store-path caching).

#define T_DIM 4096
#define B_DIM 8
#define H_DIM 512
#define M_DIM (T_DIM * B_DIM)   // 32768 rows
#define N3H 1536                // 3*H
#define K_DIM 512
#define NKT (K_DIM / 64)        // 8 K-tiles
#define NCHUNK 512
#define CLEN (T_DIM / NCHUNK)   // 8
#define NCHAIN (B_DIM * H_DIM)  // 4096
#define NGRP 32
#define GLEN (NCHUNK / NGRP)    // 16

typedef __attribute__((ext_vector_type(8))) short s16x8;   // 8 bf16 (4 VGPRs)
typedef __attribute__((ext_vector_type(4))) float f32x4;
typedef unsigned short ushort_t;
typedef unsigned int uint_t;

__device__ __forceinline__ float bf2f(ushort_t u) {
    return __uint_as_float(((uint_t)u) << 16);
}
__device__ __forceinline__ ushort_t f2bf(float f) {
    uint_t u = __float_as_uint(f);
    u += 0x7FFFu + ((u >> 16) & 1u);   // RNE
    return (ushort_t)(u >> 16);
}
__device__ __forceinline__ float frcp(float x) { return __builtin_amdgcn_rcpf(x); }
__device__ __forceinline__ float sigm(float z) {
    return frcp(1.0f + __expf(-z));
}
__device__ __forceinline__ float tanh_fast(float z) {
    return 1.0f - 2.0f * frcp(__expf(2.0f * z) + 1.0f);
}

// ---------------- fused fp32 -> bf16 convert for x, W0, W1 ----------------
#define XF4 (M_DIM * K_DIM / 4)          // 4194304 float4
#define WF4 (N3H * K_DIM / 4)            // 196608 float4
__global__ void cvt_all(const float* __restrict__ x, const float* __restrict__ w0,
                        const float* __restrict__ w1, ushort_t* __restrict__ xb,
                        ushort_t* __restrict__ w0b, ushort_t* __restrict__ w1b) {
    int i = blockIdx.x * blockDim.x + threadIdx.x;
    const float* src; ushort_t* dst; int idx;
    if (i < XF4) { src = x; dst = xb; idx = i; }
    else if (i < XF4 + WF4) { src = w0; dst = w0b; idx = i - XF4; }
    else if (i < XF4 + 2 * WF4) { src = w1; dst = w1b; idx = i - XF4 - WF4; }
    else return;
    float4 v = reinterpret_cast<const float4*>(src)[idx];
    ushort4 o;
    o.x = f2bf(v.x); o.y = f2bf(v.y); o.z = f2bf(v.z); o.w = f2bf(v.w);
    reinterpret_cast<ushort4*>(dst)[idx] = o;
}

// ---------------- bf16 GEMM 256x256 tile, BK=64, 8 waves (2Mx4N), 4-phase/K-tile ----------------
__device__ __forceinline__ s16x8 lds_swz_read(const ushort_t* base, int row, int kb) {
    int byte = (row << 7) + (((kb << 1)) ^ ((row & 7) << 4));
    return *reinterpret_cast<const s16x8*>(reinterpret_cast<const char*>(base) + byte);
}

__global__ __launch_bounds__(512, 2) void gemm_bt256(const ushort_t* __restrict__ A,
                                                     const ushort_t* __restrict__ Bm,
                                                     ushort_t* __restrict__ C) {
    __shared__ ushort_t SH[65536];               // 128 KiB
    const int ntn = N3H >> 8;                    // 6 col tiles
    const int nwg = gridDim.x;                   // 768 (%8==0)
    const int bid = (int)blockIdx.x;
    const int id = (bid & 7) * (nwg >> 3) + (bid >> 3);   // XCD swizzle (bijective)
    const int tm = id / ntn, tn = id % ntn;
    const int row0 = tm << 8, col0 = tn << 8;
    const int tid = threadIdx.x;
    const int wv = tid >> 6, lane = tid & 63;
    const int wm = wv >> 2, wn = wv & 3;         // 2M x 4N waves; wave tile 128x64
    const int l15 = lane & 15;
    const int kgrp = (lane >> 4) << 3;           // 0,8,16,24

    f32x4 acc[8][4] = {};                        // 8 m-frags x 4 n-frags of 16x16

    const int srw = lane >> 3;                   // row within 8-row wave segment
    const int ssl = lane & 7;                    // 16B slot within 128B row

#define A_OFF(buf_, hh_) ((buf_) * 16384 + (hh_) * 8192)
#define B_OFF(buf_, hh_) (32768 + (buf_) * 16384 + (hh_) * 8192)

#define STAGE_H(ISB, GP, BASE0, hh, t_, d_)                                              \
    {                                                                                    \
        _Pragma("unroll")                                                                \
        for (int j = 0; j < 2; ++j) {                                                    \
            const int rl = j * 64 + wv * 8 + srw;                                        \
            const int sl = ssl ^ (rl & 7);                                               \
            const ushort_t* gp_ = (GP) + (size_t)((BASE0) + (hh) * 128 + rl) * K_DIM     \
                                  + (t_) * 64 + (sl << 3);                               \
            ushort_t* dp_ = &SH[((ISB) ? B_OFF(d_, hh) : A_OFF(d_, hh))                  \
                                + (j * 64 + wv * 8) * 64];                               \
            __builtin_amdgcn_global_load_lds(                                            \
                (const __attribute__((address_space(1))) void*)gp_,                      \
                (__attribute__((address_space(3))) void*)dp_, 16, 0, 0);                 \
        }                                                                                \
    }

#define LDA_HALF(mbase_)                                                                 \
    _Pragma("unroll")                                                                    \
    for (int m = 0; m < 4; ++m)                                                          \
        _Pragma("unroll")                                                                \
        for (int kk = 0; kk < 2; ++kk)                                                   \
            af[m][kk] = lds_swz_read(&SH[A_OFF(buf, wm)], (mbase_ + m) * 16 + l15,       \
                                     kk * 32 + kgrp);

#define LDB_PAIR(nbase_)                                                                 \
    _Pragma("unroll")                                                                    \
    for (int n = 0; n < 2; ++n)                                                          \
        _Pragma("unroll")                                                                \
        for (int kk = 0; kk < 2; ++kk)                                                   \
            bfr[(nbase_) + n][kk] = lds_swz_read(&SH[B_OFF(buf, wn >> 1)],               \
                (wn & 1) * 64 + ((nbase_) + n) * 16 + l15, kk * 32 + kgrp);

#define MFMA_Q(mbase_, nbase_)                                                           \
    _Pragma("unroll")                                                                    \
    for (int m = 0; m < 4; ++m)                                                          \
        _Pragma("unroll")                                                                \
        for (int n = 0; n < 2; ++n)                                                      \
            _Pragma("unroll")                                                            \
            for (int kk = 0; kk < 2; ++kk)                                               \
                acc[(mbase_) + m][(nbase_) + n] = __builtin_amdgcn_mfma_f32_16x16x32_bf16( \
                    af[m][kk], bfr[(nbase_) + n][kk], acc[(mbase_) + m][(nbase_) + n],   \
                    0, 0, 0);

    STAGE_H(1, Bm, col0, 0, 0, 0);
    STAGE_H(0, A, row0, 0, 0, 0);
    STAGE_H(1, Bm, col0, 1, 0, 0);
    STAGE_H(0, A, row0, 1, 0, 0);
    STAGE_H(1, Bm, col0, 0, 1, 1);
    STAGE_H(0, A, row0, 0, 1, 1);
    asm volatile("s_waitcnt vmcnt(4)" ::: "memory");
    __builtin_amdgcn_s_barrier();

#pragma unroll
    for (int u = 0; u < NKT; ++u) {
        const int buf = u & 1;
        s16x8 af[4][2], bfr[4][2];

        LDA_HALF(0);
        LDB_PAIR(0);
        if (u + 1 < NKT) { STAGE_H(1, Bm, col0, 1, u + 1, buf ^ 1); }
        __builtin_amdgcn_s_barrier();
        asm volatile("s_waitcnt lgkmcnt(0)" ::: "memory");
        __builtin_amdgcn_s_setprio(1);
        MFMA_Q(0, 0);
        __builtin_amdgcn_s_setprio(0);
        __builtin_amdgcn_s_barrier();

        LDB_PAIR(2);
        if (u + 1 < NKT) { STAGE_H(0, A, row0, 1, u + 1, buf ^ 1); }
        __builtin_amdgcn_s_barrier();
        asm volatile("s_waitcnt lgkmcnt(0)" ::: "memory");
        __builtin_amdgcn_s_setprio(1);
        MFMA_Q(0, 2);
        __builtin_amdgcn_s_setprio(0);
        __builtin_amdgcn_s_barrier();

        LDA_HALF(4);
        if (u + 2 < NKT) { STAGE_H(1, Bm, col0, 0, u + 2, buf); }
        __builtin_amdgcn_s_barrier();
        asm volatile("s_waitcnt lgkmcnt(0)" ::: "memory");
        __builtin_amdgcn_s_setprio(1);
        MFMA_Q(4, 0);
        __builtin_amdgcn_s_setprio(0);
        __builtin_amdgcn_s_barrier();

        if (u + 2 < NKT) { STAGE_H(0, A, row0, 0, u + 2, buf); }
        __builtin_amdgcn_s_barrier();
        __builtin_amdgcn_s_setprio(1);
        MFMA_Q(4, 2);
        __builtin_amdgcn_s_setprio(0);
        if (u + 2 < NKT)      { asm volatile("s_waitcnt vmcnt(4)" ::: "memory"); }
        else if (u + 1 < NKT) { asm volatile("s_waitcnt vmcnt(0)" ::: "memory"); }
        __builtin_amdgcn_s_barrier();
    }
#undef MFMA_Q
#undef LDB_PAIR
#undef LDA_HALF
#undef STAGE_H
#undef A_OFF
#undef B_OFF

    // epilogue: stage C in LDS (col-XOR swizzle, conflict-free), coalesced cached stores
    {
        const int crow = (lane >> 4) << 2;
        const int g = (lane >> 4) & 3;
#pragma unroll
        for (int m = 0; m < 8; ++m) {
            const int rowb = wm * 128 + m * 16 + crow;
#pragma unroll
            for (int n = 0; n < 4; ++n) {
                const int pcol = wn * 64 + ((n ^ g) << 4) + l15;
#pragma unroll
                for (int v = 0; v < 4; ++v)
                    SH[(rowb + v) * 256 + pcol] = f2bf(acc[m][n][v]);
            }
        }
        __syncthreads();
#pragma unroll
        for (int i = 0; i < 16; ++i) {
            const int row = i * 16 + (tid >> 5);
            const int colE = (tid & 31) << 3;
            const int pcol = colE ^ (((row >> 2) & 3) << 4);
            s16x8 vv = *reinterpret_cast<const s16x8*>(&SH[row * 256 + pcol]);
            *reinterpret_cast<s16x8*>(&C[(size_t)(row0 + row) * N3H + col0 + colE]) = vv;
        }
    }
}

// ---------------- scan pass A: per-chunk summaries, 16B/lane ----------------
__global__ void scan_summary(const ushort_t* __restrict__ U, const float* __restrict__ bias,
                             float* __restrict__ Sa, float* __restrict__ Sb) {
    const int chunk = blockIdx.x >> 2;
    const int bp = blockIdx.x & 3;
    const int tid = threadIdx.x;
    const int b = bp * 2 + (tid >> 6);
    const int h = (tid & 63) << 3;
    float fb[8];
#pragma unroll
    for (int j = 0; j < 8; ++j) fb[j] = bias[h + j];
    float Aa[8] = {1.f, 1.f, 1.f, 1.f, 1.f, 1.f, 1.f, 1.f};
    float Bv[8] = {0.f, 0.f, 0.f, 0.f, 0.f, 0.f, 0.f, 0.f};
    const ushort_t* rp = U + ((size_t)(chunk * CLEN) * B_DIM + b) * N3H + h;
    s16x8 xt = *reinterpret_cast<const s16x8*>(rp);
    s16x8 ft = *reinterpret_cast<const s16x8*>(rp + H_DIM);
#pragma unroll
    for (int s = 0; s < CLEN; ++s) {
        s16x8 xt_n, ft_n;
        if (s + 1 < CLEN) {
            rp += (size_t)B_DIM * N3H;
            xt_n = *reinterpret_cast<const s16x8*>(rp);
            ft_n = *reinterpret_cast<const s16x8*>(rp + H_DIM);
        }
#pragma unroll
        for (int j = 0; j < 8; ++j) {
            float f = sigm(bf2f((ushort_t)ft[j]) + fb[j]);
            Aa[j] *= f;
            Bv[j] = f * Bv[j] + (1.f - f) * bf2f((ushort_t)xt[j]);
        }
        xt = xt_n; ft = ft_n;
    }
    const int cb = chunk * NCHAIN + b * H_DIM + h;
    f32x4 oA0 = {Aa[0], Aa[1], Aa[2], Aa[3]}, oA1 = {Aa[4], Aa[5], Aa[6], Aa[7]};
    f32x4 oB0 = {Bv[0], Bv[1], Bv[2], Bv[3]}, oB1 = {Bv[4], Bv[5], Bv[6], Bv[7]};
    *reinterpret_cast<f32x4*>(&Sa[cb]) = oA0;
    *reinterpret_cast<f32x4*>(&Sa[cb + 4]) = oA1;
    *reinterpret_cast<f32x4*>(&Sb[cb]) = oB0;
    *reinterpret_cast<f32x4*>(&Sb[cb + 4]) = oB1;
}

// ---------------- scan pass B1: per-group local exclusive prefixes (in-place) + group summaries ----------------
__global__ void scan_fixup1(float* Sa, float* Sb, float* __restrict__ Ga, float* __restrict__ Gb) {
    const int idx = blockIdx.x * blockDim.x + threadIdx.x;   // NGRP*4096
    const int chain = idx & (NCHAIN - 1);
    const int g = idx >> 12;
    float A = 1.f, B = 0.f;
#pragma unroll
    for (int i = 0; i < GLEN; ++i) {
        const size_t off = (size_t)(g * GLEN + i) * NCHAIN + chain;
        float a = Sa[off], b = Sb[off];
        Sa[off] = A; Sb[off] = B;       // exclusive prefix (read-before-write, thread-owned)
        B = a * B + b;
        A = a * A;
    }
    Ga[g * NCHAIN + chain] = A;
    Gb[g * NCHAIN + chain] = B;
}

// ---------------- scan pass B2: scan group summaries -> group-entry states ----------------
__global__ void scan_fixup2(const float* __restrict__ Ga, const float* __restrict__ Gb,
                            float* __restrict__ Eg, float* __restrict__ clast) {
    const int chain = blockIdx.x * blockDim.x + threadIdx.x;  // 4096
    float c = 0.f;
#pragma unroll
    for (int g = 0; g < NGRP; ++g) {
        Eg[g * NCHAIN + chain] = c;
        c = Ga[g * NCHAIN + chain] * c + Gb[g * NCHAIN + chain];
    }
    if (clast) clast[chain] = c;   // chain = b*H + h -> [B][H]
}

// ---------------- scan pass C: apply + highway, 16B/lane ----------------
template <bool IN_BF16, bool OUT_BF16>
__global__ void scan_apply(const ushort_t* __restrict__ U,
                           const float* __restrict__ bias,
                           const float* __restrict__ Sa, const float* __restrict__ Sb,
                           const float* __restrict__ Eg,
                           const void* __restrict__ xin, void* __restrict__ hout) {
    const int chunk = blockIdx.x >> 2;
    const int bp = blockIdx.x & 3;
    const int tid = threadIdx.x;
    const int b = bp * 2 + (tid >> 6);
    const int h = (tid & 63) << 3;
    const int cb = chunk * NCHAIN + b * H_DIM + h;
    const int eb = (chunk >> 4) * NCHAIN + b * H_DIM + h;   // group (GLEN=16)
    float cc[8], fb[8], rb[8];
    {
        f32x4 la0 = *reinterpret_cast<const f32x4*>(&Sa[cb]);
        f32x4 la1 = *reinterpret_cast<const f32x4*>(&Sa[cb + 4]);
        f32x4 lb0 = *reinterpret_cast<const f32x4*>(&Sb[cb]);
        f32x4 lb1 = *reinterpret_cast<const f32x4*>(&Sb[cb + 4]);
        f32x4 eg0 = *reinterpret_cast<const f32x4*>(&Eg[eb]);
        f32x4 eg1 = *reinterpret_cast<const f32x4*>(&Eg[eb + 4]);
#pragma unroll
        for (int j = 0; j < 4; ++j) {
            cc[j] = lb0[j] + la0[j] * eg0[j];
            cc[4 + j] = lb1[j] + la1[j] * eg1[j];
        }
    }
#pragma unroll
    for (int j = 0; j < 8; ++j) {
        fb[j] = bias[h + j];
        rb[j] = bias[H_DIM + h + j];
    }
    size_t row = (size_t)(chunk * CLEN) * B_DIM + b;
    const ushort_t* rp = U + row * N3H + h;
    size_t xoff = row * H_DIM + h;

    s16x8 xt = *reinterpret_cast<const s16x8*>(rp);
    s16x8 ft = *reinterpret_cast<const s16x8*>(rp + H_DIM);
    s16x8 rt = *reinterpret_cast<const s16x8*>(rp + 2 * H_DIM);
    float xv[8];
    if (IN_BF16) {
        s16x8 xi = *reinterpret_cast<const s16x8*>((const ushort_t*)xin + xoff);
#pragma unroll
        for (int j = 0; j < 8; ++j) xv[j] = bf2f((ushort_t)xi[j]);
    } else {
        f32x4 a = *reinterpret_cast<const f32x4*>((const float*)xin + xoff);
        f32x4 c2 = *reinterpret_cast<const f32x4*>((const float*)xin + xoff + 4);
#pragma unroll
        for (int j = 0; j < 4; ++j) { xv[j] = a[j]; xv[4 + j] = c2[j]; }
    }

#pragma unroll
    for (int s = 0; s < CLEN; ++s) {
        s16x8 xt_n, ft_n, rt_n;
        float xv_n[8];
        if (s + 1 < CLEN) {
            rp += (size_t)B_DIM * N3H;
            xt_n = *reinterpret_cast<const s16x8*>(rp);
            ft_n = *reinterpret_cast<const s16x8*>(rp + H_DIM);
            rt_n = *reinterpret_cast<const s16x8*>(rp + 2 * H_DIM);
            size_t xo2 = xoff + (size_t)B_DIM * H_DIM;
            if (IN_BF16) {
                s16x8 xi = *reinterpret_cast<const s16x8*>((const ushort_t*)xin + xo2);
#pragma unroll
                for (int j = 0; j < 8; ++j) xv_n[j] = bf2f((ushort_t)xi[j]);
            } else {
                f32x4 a = *reinterpret_cast<const f32x4*>((const float*)xin + xo2);
                f32x4 c2 = *reinterpret_cast<const f32x4*>((const float*)xin + xo2 + 4);
#pragma unroll
                for (int j = 0; j < 4; ++j) { xv_n[j] = a[j]; xv_n[4 + j] = c2[j]; }
            }
        }
        float hv[8];
#pragma unroll
        for (int j = 0; j < 8; ++j) {
            float f = sigm(bf2f((ushort_t)ft[j]) + fb[j]);
            cc[j] = f * cc[j] + (1.f - f) * bf2f((ushort_t)xt[j]);
            float r = sigm(bf2f((ushort_t)rt[j]) + rb[j]);
            hv[j] = r * tanh_fast(cc[j]) + (1.f - r) * xv[j];
        }
        if (OUT_BF16) {
            s16x8 o;
#pragma unroll
            for (int j = 0; j < 8; ++j) o[j] = (short)f2bf(hv[j]);
            *reinterpret_cast<s16x8*>((ushort_t*)hout + xoff) = o;
        } else {
            f32x4 o0 = {hv[0], hv[1], hv[2], hv[3]};
            f32x4 o1 = {hv[4], hv[5], hv[6], hv[7]};
            *reinterpret_cast<f32x4*>((float*)hout + xoff) = o0;
            *reinterpret_cast<f32x4*>((float*)hout + xoff + 4) = o1;
        }
        xoff += (size_t)B_DIM * H_DIM;
        xt = xt_n; ft = ft_n; rt = rt_n;
#pragma unroll
        for (int j = 0; j < 8; ++j) xv[j] = xv_n[j];
    }
}

extern "C" void kernel_launch(void* const* d_in, const int* in_sizes, int n_in,
                              void* d_out, int out_size, void* d_ws, size_t ws_size,
                              hipStream_t stream) {
    (void)in_sizes; (void)n_in; (void)out_size; (void)ws_size;
    const float* x  = (const float*)d_in[0];   // [T,B,512]
    const float* W0 = (const float*)d_in[1];   // [1536,512]
    const float* b0 = (const float*)d_in[2];   // [1024]
    const float* W1 = (const float*)d_in[3];   // [1536,512]
    const float* b1 = (const float*)d_in[4];   // [1024]
    float* out = (float*)d_out;                // h [T,B,512] fp32, then c_last [B,512] fp32

    // ws layout (bytes); total 163 MiB.
    // [0,32M): xb (bf16 x) -- dead after GEMM1; Sa/Sb/Ga/Gb/Eg alias here afterwards
    char* ws = (char*)d_ws;
    ushort_t* xb  = (ushort_t*)(ws);
    float*    Sa  = (float*)(ws);                 // 8 MiB
    float*    Sb  = (float*)(ws + 8388608);       // 8 MiB
    float*    Ga  = (float*)(ws + 16777216);      // 512 KiB
    float*    Gb  = (float*)(ws + 17301504);      // 512 KiB
    float*    Eg  = (float*)(ws + 17825792);      // 512 KiB
    ushort_t* h1  = (ushort_t*)(ws + 33554432);   // 32 MiB
    ushort_t* W0b = (ushort_t*)(ws + 67108864);   // 1.5 MiB
    ushort_t* W1b = (ushort_t*)(ws + 68681728);   // 1.5 MiB
    ushort_t* U   = (ushort_t*)(ws + 70254592);   // 96 MiB

    const int cvt_total = XF4 + 2 * WF4;
    cvt_all<<<(cvt_total + 255) / 256, 256, 0, stream>>>(x, W0, W1, xb, W0b, W1b);

    const int gemm_grid = (M_DIM / 256) * (N3H / 256);   // 768 (%8==0)
    const int scan_grid = NCHUNK * 4;                     // 2048 (chunk x batch-pair)

    // ---- layer 1 ----
    gemm_bt256<<<gemm_grid, 512, 0, stream>>>(xb, W0b, U);
    scan_summary<<<scan_grid, 128, 0, stream>>>(U, b0, Sa, Sb);
    scan_fixup1<<<NGRP * NCHAIN / 256, 256, 0, stream>>>(Sa, Sb, Ga, Gb);
    scan_fixup2<<<NCHAIN / 256, 256, 0, stream>>>(Ga, Gb, Eg, nullptr);
    scan_apply<false, true><<<scan_grid, 128, 0, stream>>>(U, b0, Sa, Sb, Eg, (const void*)x, (void*)h1);

    // ---- layer 2 ----
    gemm_bt256<<<gemm_grid, 512, 0, stream>>>(h1, W1b, U);
    scan_summary<<<scan_grid, 128, 0, stream>>>(U, b1, Sa, Sb);
    scan_fixup1<<<NGRP * NCHAIN / 256, 256, 0, stream>>>(Sa, Sb, Ga, Gb);
    scan_fixup2<<<NCHAIN / 256, 256, 0, stream>>>(Ga, Gb, Eg, out + (size_t)M_DIM * H_DIM);
    scan_apply<true, false><<<scan_grid, 128, 0, stream>>>(U, b1, Sa, Sb, Eg, (const void*)h1, (void*)out);
}